// Round 17
// baseline (1997.507 us; speedup 1.0000x reference)
//
#include <hip/hip_runtime.h>
#include <hip/hip_bf16.h>

#define D_MODEL   1024
#define D_STATE   16
#define D_HEAD    64
#define D_CONV    4
#define FFN_DIM   2816
#define D_INNER   2048
#define N_HEADS   32
#define BATCH     4
#define SEQ       2048
#define ROWS      (BATCH*SEQ)     // 8192
#define PROJ_DIM  4160
#define ZX_N      4096            // z + x only
#define CH        128             // scan chunk length
#define NCH       (SEQ/CH)        // 16 chunks
#define GU_N      5632            // 2*FFN_DIM interleaved (44 tiles of 128)

typedef __bf16 bf16x8 __attribute__((ext_vector_type(8)));
typedef float  f32x4  __attribute__((ext_vector_type(4)));
typedef float  f32x2  __attribute__((ext_vector_type(2)));

__device__ __forceinline__ float siluf(float x) { return x / (1.0f + __expf(-x)); }

#define SBAR() do { asm volatile("" ::: "memory"); __builtin_amdgcn_s_barrier(); asm volatile("" ::: "memory"); } while (0)
#define LGKM0() asm volatile("s_waitcnt lgkmcnt(0)" ::: "memory")
#define VMCNT4() asm volatile("s_waitcnt vmcnt(4)" ::: "memory")
#define VMCNT2() asm volatile("s_waitcnt vmcnt(2)" ::: "memory")
#define VMCNT0() asm volatile("s_waitcnt vmcnt(0)" ::: "memory")

// ---------------------------------------------------------------- all weight conversions in ONE dispatch
#define Z1 (ZX_N * D_MODEL)
#define Z2 (D_MODEL * D_INNER)
#define Z3 (GU_N * D_MODEL)
#define Z4 (D_MODEL * FFN_DIM)
__global__ void cvtall_k(const float* __restrict__ wi, const float* __restrict__ wo,
                         const float* __restrict__ wg, const float* __restrict__ wu,
                         const float* __restrict__ wd,
                         __hip_bfloat16* __restrict__ wbi, __hip_bfloat16* __restrict__ wbo,
                         __hip_bfloat16* __restrict__ wgu, __hip_bfloat16* __restrict__ wbd) {
  int i = blockIdx.x * blockDim.x + threadIdx.x;
  if (i < Z1) {
    wbi[i] = __float2bfloat16(wi[i]);
  } else if (i < Z1 + Z2) {
    int j = i - Z1;
    wbo[j] = __float2bfloat16(wo[j]);
  } else if (i < Z1 + Z2 + Z3) {
    int j = i - Z1 - Z2;
    int r = j >> 10, c = j & 1023;
    int tile = r >> 7, rr = r & 127;
    const float* src = (rr < 64)
        ? wg + (size_t)(tile * 64 + rr) * D_MODEL + c
        : wu + (size_t)(tile * 64 + (rr - 64)) * D_MODEL + c;
    wgu[j] = __float2bfloat16(*src);
  } else if (i < Z1 + Z2 + Z3 + Z4) {
    int j = i - Z1 - Z2 - Z3;
    wbd[j] = __float2bfloat16(wd[j]);
  }
}

// ---------------------------------------------------------------- rmsnorm
__global__ __launch_bounds__(256) void rmsnorm_k(const float* __restrict__ x,
                                                 const float* __restrict__ w,
                                                 __hip_bfloat16* __restrict__ out,
                                                 float* __restrict__ outf) {
  int row = blockIdx.x;
  int t = threadIdx.x;
  const float* xr = x + (size_t)row * D_MODEL;
  float4 v = ((const float4*)xr)[t];
  float ss = v.x*v.x + v.y*v.y + v.z*v.z + v.w*v.w;
  #pragma unroll
  for (int o = 32; o > 0; o >>= 1) ss += __shfl_xor(ss, o);
  __shared__ float red[4];
  if ((t & 63) == 0) red[t >> 6] = ss;
  __syncthreads();
  ss = red[0] + red[1] + red[2] + red[3];
  float scale = rsqrtf(ss * (1.0f / D_MODEL) + 1e-6f);
  float4 wv = ((const float4*)w)[t];
  float4 r;
  r.x = v.x * scale * wv.x; r.y = v.y * scale * wv.y;
  r.z = v.z * scale * wv.z; r.w = v.w * scale * wv.w;
  __hip_bfloat16* orow = out + (size_t)row * D_MODEL + t * 4;
  orow[0] = __float2bfloat16(r.x);
  orow[1] = __float2bfloat16(r.y);
  orow[2] = __float2bfloat16(r.z);
  orow[3] = __float2bfloat16(r.w);
  if (outf) ((float4*)(outf + (size_t)row * D_MODEL))[t] = r;
}

// ---------------------------------------------------------------- dt + B/C projection (pure f32, block-per-4-rows)
__global__ __launch_bounds__(256) void vecproj_k(const float* __restrict__ xn,
                                                 const float* __restrict__ wi,
                                                 const float* __restrict__ dtb,
                                                 float* __restrict__ dtT,
                                                 float* __restrict__ bcraw) {
  const int r0 = blockIdx.x * 4;
  const int t  = threadIdx.x;
  const int o   = t >> 2;
  const int seg = t & 3;

  __shared__ float xs[4][D_MODEL];
  #pragma unroll
  for (int i = 0; i < 4; ++i)
    ((float4*)&xs[i][0])[t] = ((const float4*)(xn + (size_t)(r0 + i) * D_MODEL))[t];
  __syncthreads();

  const int wrow = (o < 32) ? (2 * D_INNER + o) : (2 * D_INNER + 2 * D_STATE + (o - 32));
  const float4* w4 = (const float4*)(wi + (size_t)wrow * D_MODEL) + seg * 64;
  const float4* x0 = (const float4*)&xs[0][0] + seg * 64;
  const float4* x1 = (const float4*)&xs[1][0] + seg * 64;
  const float4* x2 = (const float4*)&xs[2][0] + seg * 64;
  const float4* x3 = (const float4*)&xs[3][0] + seg * 64;
  float a0 = 0.f, a1 = 0.f, a2 = 0.f, a3 = 0.f;
  #pragma unroll 8
  for (int k = 0; k < 64; ++k) {
    float4 wv = w4[k];
    float4 v0 = x0[k], v1 = x1[k], v2 = x2[k], v3 = x3[k];
    a0 = fmaf(wv.x, v0.x, fmaf(wv.y, v0.y, fmaf(wv.z, v0.z, fmaf(wv.w, v0.w, a0))));
    a1 = fmaf(wv.x, v1.x, fmaf(wv.y, v1.y, fmaf(wv.z, v1.z, fmaf(wv.w, v1.w, a1))));
    a2 = fmaf(wv.x, v2.x, fmaf(wv.y, v2.y, fmaf(wv.z, v2.z, fmaf(wv.w, v2.w, a2))));
    a3 = fmaf(wv.x, v3.x, fmaf(wv.y, v3.y, fmaf(wv.z, v3.z, fmaf(wv.w, v3.w, a3))));
  }
  #pragma unroll
  for (int m = 1; m < 4; m <<= 1) {
    a0 += __shfl_xor(a0, m);
    a1 += __shfl_xor(a1, m);
    a2 += __shfl_xor(a2, m);
    a3 += __shfl_xor(a3, m);
  }
  if (seg == 0) {
    float v[4] = {a0, a1, a2, a3};
    if (o < 32) {
      #pragma unroll
      for (int i = 0; i < 4; ++i) bcraw[(size_t)(r0 + i) * 32 + o] = v[i];
    } else {
      int hh = o - 32;
      float bias = dtb[hh];
      #pragma unroll
      for (int i = 0; i < 4; ++i) {
        float xv = v[i] + bias;
        dtT[(size_t)hh * ROWS + r0 + i] = (xv > 20.f) ? xv : log1pf(__expf(xv));
      }
    }
  }
}

// ---------------------------------------------------------------- 256x256 8-phase GEMM (counted vmcnt)
// EPI: 5 plain bf16 store.
template<int EPI>
__global__ __launch_bounds__(512, 2) void gemm8(
    const __hip_bfloat16* __restrict__ A,
    const __hip_bfloat16* __restrict__ Bw,
    __hip_bfloat16* __restrict__ Cb,
    int M, int N, int K)
{
  extern __shared__ char lds[];
  const int nwg = (M >> 8) * (N >> 8);
  int bid = blockIdx.x;
  bid = (bid & 7) * (nwg >> 3) + (bid >> 3);
  const int ntn = N >> 8;
  const int bm = (bid / ntn) << 8;
  const int bn = (bid % ntn) << 8;

  const int tid  = threadIdx.x;
  const int wid  = tid >> 6;
  const int lane = tid & 63;
  const int wm = wid >> 2;
  const int wn = wid & 3;
  const int r16 = lane & 15;
  const int kg  = lane >> 4;

  const int rb = ((r16 << 6) + (kg << 4)) ^ ((r16 & 8) << 2);

  const int s_sub = tid >> 6;
  const int s_w   = (tid & 63) << 4;
  const int s_wp  = s_w ^ ((((s_w) >> 9) & 1) << 5);
  const int s_row = ((s_sub >> 1) << 4) + (s_wp >> 6);
  const int s_col = ((s_sub & 1) << 5) + ((s_wp >> 1) & 31);

  auto stage = [&](int buf, int mat, int half, int c, int kt) {
    const __hip_bfloat16* src = (mat == 0)
        ? A  + (size_t)(bm + half * 128 + c * 64 + s_row) * K + kt * 64 + s_col
        : Bw + (size_t)(bn + half * 128 + c * 64 + s_row) * K + kt * 64 + s_col;
    char* dst = lds + buf * 65536 + mat * 32768 + half * 16384 + c * 8192 + tid * 16;
    __builtin_amdgcn_global_load_lds((const __attribute__((address_space(1))) unsigned int*)src,
                                     (__attribute__((address_space(3))) unsigned int*)dst,
                                     16, 0, 0);
  };

  f32x4 acc[8][4] = {};
  bf16x8 af[4][2], bfr[4][2];

  const int NT = K >> 6;
  stage(0,0,0,0,0); stage(0,0,0,1,0); stage(0,0,1,0,0); stage(0,0,1,1,0);
  stage(0,1,0,0,0); stage(0,1,0,1,0); stage(0,1,1,0,0); stage(0,1,1,1,0);
  __syncthreads();

  for (int kt = 0; kt < NT; ++kt) {
    const int buf = kt & 1, nbuf = buf ^ 1;
    const bool st = (kt + 1 < NT);
    const char* Ab = lds + buf * 65536 + wm * 16384;
    const char* Bb = lds + buf * 65536 + 32768 + (wn >> 1) * 16384 + (wn & 1) * 8192;

    #pragma unroll
    for (int mi2 = 0; mi2 < 4; ++mi2)
      #pragma unroll
      for (int kk = 0; kk < 2; ++kk)
        af[mi2][kk] = *(const bf16x8*)(Ab + (mi2 * 2 + kk) * 1024 + rb);
    #pragma unroll
    for (int ni = 0; ni < 2; ++ni)
      #pragma unroll
      for (int kk = 0; kk < 2; ++kk)
        bfr[ni][kk] = *(const bf16x8*)(Bb + (ni * 2 + kk) * 1024 + rb);
    if (st) { stage(nbuf,1,0,0,kt+1); stage(nbuf,1,0,1,kt+1); }
    SBAR(); LGKM0();
    __builtin_amdgcn_s_setprio(1);
    #pragma unroll
    for (int mi2 = 0; mi2 < 4; ++mi2)
      #pragma unroll
      for (int ni = 0; ni < 2; ++ni)
        #pragma unroll
        for (int kk = 0; kk < 2; ++kk)
          acc[mi2][ni] = __builtin_amdgcn_mfma_f32_16x16x32_bf16(af[mi2][kk], bfr[ni][kk], acc[mi2][ni], 0, 0, 0);
    __builtin_amdgcn_s_setprio(0);
    SBAR();

    #pragma unroll
    for (int ni = 2; ni < 4; ++ni)
      #pragma unroll
      for (int kk = 0; kk < 2; ++kk)
        bfr[ni][kk] = *(const bf16x8*)(Bb + (ni * 2 + kk) * 1024 + rb);
    if (st) { stage(nbuf,1,1,0,kt+1); stage(nbuf,1,1,1,kt+1); }
    SBAR(); LGKM0();
    __builtin_amdgcn_s_setprio(1);
    #pragma unroll
    for (int mi2 = 0; mi2 < 4; ++mi2)
      #pragma unroll
      for (int ni = 2; ni < 4; ++ni)
        #pragma unroll
        for (int kk = 0; kk < 2; ++kk)
          acc[mi2][ni] = __builtin_amdgcn_mfma_f32_16x16x32_bf16(af[mi2][kk], bfr[ni][kk], acc[mi2][ni], 0, 0, 0);
    __builtin_amdgcn_s_setprio(0);
    if (st) { VMCNT4(); } else { VMCNT0(); }
    SBAR();

    #pragma unroll
    for (int mi2 = 0; mi2 < 4; ++mi2)
      #pragma unroll
      for (int kk = 0; kk < 2; ++kk)
        af[mi2][kk] = *(const bf16x8*)(Ab + ((4 + mi2) * 2 + kk) * 1024 + rb);
    if (st) { stage(nbuf,0,0,0,kt+1); stage(nbuf,0,1,0,kt+1); }
    SBAR(); LGKM0();
    __builtin_amdgcn_s_setprio(1);
    #pragma unroll
    for (int mi2 = 0; mi2 < 4; ++mi2)
      #pragma unroll
      for (int ni = 0; ni < 2; ++ni)
        #pragma unroll
        for (int kk = 0; kk < 2; ++kk)
          acc[4 + mi2][ni] = __builtin_amdgcn_mfma_f32_16x16x32_bf16(af[mi2][kk], bfr[ni][kk], acc[4 + mi2][ni], 0, 0, 0);
    __builtin_amdgcn_s_setprio(0);
    SBAR();

    if (st) { stage(nbuf,0,0,1,kt+1); stage(nbuf,0,1,1,kt+1); }
    SBAR(); LGKM0();
    __builtin_amdgcn_s_setprio(1);
    #pragma unroll
    for (int mi2 = 0; mi2 < 4; ++mi2)
      #pragma unroll
      for (int ni = 2; ni < 4; ++ni)
        #pragma unroll
        for (int kk = 0; kk < 2; ++kk)
          acc[4 + mi2][ni] = __builtin_amdgcn_mfma_f32_16x16x32_bf16(af[mi2][kk], bfr[ni][kk], acc[4 + mi2][ni], 0, 0, 0);
    __builtin_amdgcn_s_setprio(0);
    VMCNT2();
    SBAR();
  }

  #pragma unroll
  for (int mi = 0; mi < 8; ++mi) {
    #pragma unroll
    for (int ni = 0; ni < 4; ++ni) {
      #pragma unroll
      for (int j = 0; j < 4; ++j) {
        int r = bm + wm * 128 + mi * 16 + kg * 4 + j;
        int c = bn + wn * 64 + ni * 16 + r16;
        Cb[(size_t)r * N + c] = __float2bfloat16(acc[mi][ni][j]);
      }
    }
  }
}

// ---------------------------------------------------------------- 256x128 BK=32 GEMM, 2-deep, 3 blocks/CU
// EPI: 4 fused gate/up (bf16 LDS exchange, silu(g)*u); 1 f32 store + add_src.
template<int EPI>
__global__ __launch_bounds__(512, 6) void gemmT(
    const __hip_bfloat16* __restrict__ A,
    const __hip_bfloat16* __restrict__ Bw,
    __hip_bfloat16* __restrict__ Cb,
    float* __restrict__ Cf,
    const float* __restrict__ add_src,
    int M, int N, int K)
{
  extern __shared__ char lds[];          // 49152
  const int nwg = (M >> 8) * (N >> 7);
  int bid = blockIdx.x;
  bid = (bid & 7) * (nwg >> 3) + (bid >> 3);
  const int ntn = N >> 7;
  const int bm = (bid / ntn) << 8;
  const int bn = (bid % ntn) << 7;

  const int tid  = threadIdx.x;
  const int wid  = tid >> 6;
  const int lane = tid & 63;
  const int wm = wid >> 1;          // 0..3
  const int wn = wid & 1;           // 0..1
  const int r16 = lane & 15;
  const int kg  = lane >> 4;

  const int rb = ((r16 << 6) + (kg << 4)) ^ ((r16 & 8) << 2);

  const int s_sub = tid >> 6;
  const int s_w   = (tid & 63) << 4;
  const int s_wp  = s_w ^ ((((s_w) >> 9) & 1) << 5);
  const int s_row = (s_sub << 4) + (s_wp >> 6);
  const int s_col = (s_wp >> 1) & 31;

  auto stageA = [&](int buf, int h, int kt) {
    const __hip_bfloat16* src = A + (size_t)(bm + h * 128 + s_row) * K + kt * 32 + s_col;
    char* dst = lds + buf * 24576 + h * 8192 + tid * 16;
    __builtin_amdgcn_global_load_lds((const __attribute__((address_space(1))) unsigned int*)src,
                                     (__attribute__((address_space(3))) unsigned int*)dst,
                                     16, 0, 0);
  };
  auto stageB = [&](int buf, int kt) {
    const __hip_bfloat16* src = Bw + (size_t)(bn + s_row) * K + kt * 32 + s_col;
    char* dst = lds + buf * 24576 + 16384 + tid * 16;
    __builtin_amdgcn_global_load_lds((const __attribute__((address_space(1))) unsigned int*)src,
                                     (__attribute__((address_space(3))) unsigned int*)dst,
                                     16, 0, 0);
  };

  f32x4 acc[4][4] = {};

  const int NT = K >> 5;
  stageA(0, 0, 0); stageA(0, 1, 0); stageB(0, 0);
  __syncthreads();

  for (int kt = 0; kt < NT; ++kt) {
    const int buf = kt & 1, nbuf = buf ^ 1;
    const bool st = (kt + 1 < NT);
    const char* Ab = lds + buf * 24576 + wm * 4096;
    const char* Bb = lds + buf * 24576 + 16384 + wn * 4096;

    bf16x8 af[4], bfr[4];
    #pragma unroll
    for (int mi = 0; mi < 4; ++mi) af[mi]  = *(const bf16x8*)(Ab + mi * 1024 + rb);
    #pragma unroll
    for (int ni = 0; ni < 4; ++ni) bfr[ni] = *(const bf16x8*)(Bb + ni * 1024 + rb);
    if (st) { stageA(nbuf, 0, kt + 1); stageA(nbuf, 1, kt + 1); stageB(nbuf, kt + 1); }
    __builtin_amdgcn_s_setprio(1);
    #pragma unroll
    for (int mi = 0; mi < 4; ++mi)
      #pragma unroll
      for (int ni = 0; ni < 4; ++ni)
        acc[mi][ni] = __builtin_amdgcn_mfma_f32_16x16x32_bf16(af[mi], bfr[ni], acc[mi][ni], 0, 0, 0);
    __builtin_amdgcn_s_setprio(0);
    VMCNT0();
    SBAR();
  }

  if constexpr (EPI == 4) {
    __hip_bfloat16* xch = (__hip_bfloat16*)lds;   // [256][72] bf16
    __syncthreads();
    if (wn == 0) {
      #pragma unroll
      for (int mi = 0; mi < 4; ++mi)
        #pragma unroll
        for (int ni = 0; ni < 4; ++ni)
          #pragma unroll
          for (int j = 0; j < 4; ++j) {
            int row = wm * 64 + mi * 16 + kg * 4 + j;
            int col = ni * 16 + r16;
            xch[row * 72 + col] = __float2bfloat16(siluf(acc[mi][ni][j]));
          }
    }
    __syncthreads();
    if (wn == 1) {
      #pragma unroll
      for (int mi = 0; mi < 4; ++mi)
        #pragma unroll
        for (int ni = 0; ni < 4; ++ni)
          #pragma unroll
          for (int j = 0; j < 4; ++j) {
            int row = wm * 64 + mi * 16 + kg * 4 + j;
            int col = ni * 16 + r16;
            float g = __bfloat162float(xch[row * 72 + col]);
            Cb[(size_t)(bm + row) * FFN_DIM + (bn >> 1) + col] =
                __float2bfloat16(g * acc[mi][ni][j]);
          }
    }
  } else if constexpr (EPI == 1) {
    #pragma unroll
    for (int mi = 0; mi < 4; ++mi)
      #pragma unroll
      for (int ni = 0; ni < 4; ++ni)
        #pragma unroll
        for (int j = 0; j < 4; ++j) {
          int r = bm + wm * 64 + mi * 16 + kg * 4 + j;
          int c = bn + wn * 64 + ni * 16 + r16;
          size_t idx = (size_t)r * N + c;
          Cf[idx] = acc[mi][ni][j] + add_src[idx];
        }
  } else {
    #pragma unroll
    for (int mi = 0; mi < 4; ++mi)
      #pragma unroll
      for (int ni = 0; ni < 4; ++ni)
        #pragma unroll
        for (int j = 0; j < 4; ++j) {
          int r = bm + wm * 64 + mi * 16 + kg * 4 + j;
          int c = bn + wn * 64 + ni * 16 + r16;
          Cb[(size_t)r * N + c] = __float2bfloat16(acc[mi][ni][j]);
        }
  }
}

// ---------------------------------------------------------------- u = silu(depthwise conv(x)), x in bf16, u bf16 -> po
__global__ __launch_bounds__(256) void duconv_k(const __hip_bfloat16* __restrict__ zxb,
                                                const float* __restrict__ cw,
                                                const float* __restrict__ cb,
                                                __hip_bfloat16* __restrict__ u_po) {
  int idx = blockIdx.x * 256 + threadIdx.x;
  int q = idx & 511;
  int r = idx >> 9;
  int d0 = q << 2;
  int l = r & (SEQ - 1);
  float4 cb4 = ((const float4*)cb)[q];
  float tw[4][4];
  #pragma unroll
  for (int i = 0; i < 4; ++i) {
    float4 t = ((const float4*)cw)[d0 + i];
    tw[i][0] = t.x; tw[i][1] = t.y; tw[i][2] = t.z; tw[i][3] = t.w;
  }
  float a[4] = {cb4.x, cb4.y, cb4.z, cb4.w};
  #pragma unroll
  for (int k = 0; k < 4; ++k) {
    if (l - 3 + k >= 0) {
      union { ushort4 u4; __hip_bfloat16 b[4]; } R;
      R.u4 = *(const ushort4*)(zxb + (size_t)(r - 3 + k) * ZX_N + D_INNER + d0);
      a[0] = fmaf(__bfloat162float(R.b[0]), tw[0][k], a[0]);
      a[1] = fmaf(__bfloat162float(R.b[1]), tw[1][k], a[1]);
      a[2] = fmaf(__bfloat162float(R.b[2]), tw[2][k], a[2]);
      a[3] = fmaf(__bfloat162float(R.b[3]), tw[3][k], a[3]);
    }
  }
  union { ushort4 u4; __hip_bfloat16 b[4]; } pk;
  #pragma unroll
  for (int i = 0; i < 4; ++i) pk.b[i] = __float2bfloat16(siluf(a[i]));
  *(ushort4*)(u_po + (size_t)r * D_INNER + d0) = pk.u4;
}

// ---------------------------------------------------------------- conv+silu+normalize for the 32 B/C channels
__global__ __launch_bounds__(256) void bcdt_k(const float* __restrict__ bcraw,
                                              const float* __restrict__ cw,
                                              const float* __restrict__ cb,
                                              float* __restrict__ bc) {
  int t = threadIdx.x;
  int r = blockIdx.x * 8 + (t >> 5);
  int ch = t & 31;
  int l = r & (SEQ - 1);
  int c = D_INNER + ch;
  float acc = cb[c];
  #pragma unroll
  for (int k = 0; k < 4; ++k) {
    int lp = l - 3 + k;
    if (lp >= 0)
      acc = fmaf(bcraw[(size_t)(r - 3 + k) * 32 + ch], cw[c * 4 + k], acc);
  }
  acc = siluf(acc);
  float ss = acc * acc;
  ss += __shfl_xor(ss, 1);
  ss += __shfl_xor(ss, 2);
  ss += __shfl_xor(ss, 4);
  ss += __shfl_xor(ss, 8);
  bc[r * 32 + ch] = acc / (sqrtf(ss) + 1e-6f);
}

// ---------------------------------------------------------------- chunk transfer matrices
__global__ __launch_bounds__(256) void pk_k(const float* __restrict__ dtT,
                                            const float* __restrict__ A_log,
                                            float* __restrict__ Pm) {
  int bh = blockIdx.x;
  int h = bh & 31;
  int t = threadIdx.x;
  int ch = t >> 4, n = t & 15;
  float a = __expf(A_log[h * 16 + n]);
  const float* dtp = dtT + (size_t)h * ROWS + (size_t)(bh >> 5) * SEQ + ch * CH;
  float p00 = 1.f, p01 = 0.f, p10 = 0.f, p11 = 1.f;
  for (int l = 0; l < CH; ++l) {
    float dt = dtp[l];
    float s  = 1.0f / fmaf(dt * dt, a, 1.0f);
    float m00 = s;
    float m01 = -dt * a * s;
    float m10 = dt * s;
    float m11 = fmaf(-dt * a, m10, 1.0f);
    float q00 = fmaf(m00, p00, m01 * p10);
    float q01 = fmaf(m00, p01, m01 * p11);
    float q10 = fmaf(m10, p00, m11 * p10);
    float q11 = fmaf(m10, p01, m11 * p11);
    p00 = q00; p01 = q01; p10 = q10; p11 = q11;
  }
  float4 v = {p00, p01, p10, p11};
  *(float4*)&Pm[(((size_t)bh * NCH + ch) * 16 + n) * 4] = v;
}

// ---------------------------------------------------------------- propagate chunk-boundary states
__global__ __launch_bounds__(256) void prop_k(const float* __restrict__ Pm,
                                              const float* __restrict__ pend,
                                              float* __restrict__ sinit) {
  int gid = blockIdx.x * 256 + threadIdx.x;
  int n  = gid & 15;
  int d  = (gid >> 4) & 63;
  int bh = gid >> 10;
  float s0 = 0.f, s1 = 0.f;
  for (int c = 0; c < NCH; ++c) {
    size_t i2 = (((size_t)bh * NCH + c) * 64 + d) * 16 + n;
    *(float2*)&sinit[i2 * 2] = make_float2(s0, s1);
    float4 P  = *(const float4*)&Pm[(((size_t)bh * NCH + c) * 16 + n) * 4];
    float2 pe = *(const float2*)&pend[i2 * 2];
    float t0 = fmaf(P.x, s0, fmaf(P.y, s1, pe.x));
    float t1 = fmaf(P.z, s0, fmaf(P.w, s1, pe.y));
    s0 = t0; s1 = t1;
  }
}

// ---------------------------------------------------------------- chunked scan (u precomputed, f32x2 packed recurrence)
#define T_TILE 16
#define TPC (CH / T_TILE)
template<int PHASE>
__global__ __launch_bounds__(128) void scan_k(
    const __hip_bfloat16* __restrict__ zxb, const float* __restrict__ bcb,
    const float* __restrict__ dtT, const float* __restrict__ A_log,
    const float* __restrict__ Dp, float* __restrict__ states,
    __hip_bfloat16* u_po)
{
  const int blk  = blockIdx.x;
  const int half = blk & 1;
  const int ch   = (blk >> 1) & 15;
  const int h    = (blk >> 5) & 31;
  const int b    = blk >> 10;
  const int bh   = b * 32 + h;
  const int tid  = threadIdx.x;
  const int wv   = tid >> 6;
  const int lane = tid & 63;
  const int d16  = lane & 15;
  const int ng   = lane >> 4;
  const int n0   = ng * 4;
  const int dwv  = wv * 16 + d16;
  const int dl   = half * 32 + dwv;
  const int dbase = h * 64 + half * 32;
  const size_t rowbase = (size_t)b * SEQ + (size_t)ch * CH;

  __shared__ __hip_bfloat16 dut[2][T_TILE][32];
  __shared__ float Btl[2][T_TILE][16];
  __shared__ float Ctl[PHASE == 3 ? 2 : 1][T_TILE][16];
  __shared__ __hip_bfloat16 zt [PHASE == 3 ? 2 : 1][T_TILE][32];
  __shared__ float st [2][T_TILE][16];
  __shared__ float dtt[2][T_TILE];
  __shared__ float aexp[16];
  __shared__ float opart[PHASE == 3 ? T_TILE : 1][32][4];

  if (tid < 16) aexp[tid] = __expf(A_log[h * 16 + tid]);

  f32x2 A2[2];
  #pragma unroll
  for (int k = 0; k < 2; ++k) {
    A2[k][0] = __expf(A_log[h * 16 + n0 + 2 * k]);
    A2[k][1] = __expf(A_log[h * 16 + n0 + 2 * k + 1]);
  }
  const float Dh = Dp[h];

  auto stage = [&](int tile, int buf) {
    const size_t r0 = rowbase + (size_t)tile * T_TILE;
    if constexpr (PHASE == 3) {
      if (wv == 0) {
        const __hip_bfloat16* g = u_po + (r0 + (lane >> 2)) * D_INNER + dbase + (lane & 3) * 8;
        __hip_bfloat16* l_ = &dut[buf][0][0] + lane * 8;
        __builtin_amdgcn_global_load_lds((const __attribute__((address_space(1))) unsigned int*)g,
                                         (__attribute__((address_space(3))) unsigned int*)l_, 16, 0, 0);
      } else {
        const __hip_bfloat16* gz = zxb + (r0 + (lane >> 2)) * ZX_N + dbase + (lane & 3) * 8;
        __hip_bfloat16* lz = &zt[buf][0][0] + lane * 8;
        __builtin_amdgcn_global_load_lds((const __attribute__((address_space(1))) unsigned int*)gz,
                                         (__attribute__((address_space(3))) unsigned int*)lz, 16, 0, 0);
        const float* gB = bcb + (r0 + (lane >> 2)) * 32 + (lane & 3) * 4;
        float* lB = &Btl[buf][0][0] + lane * 4;
        __builtin_amdgcn_global_load_lds((const __attribute__((address_space(1))) unsigned int*)gB,
                                         (__attribute__((address_space(3))) unsigned int*)lB, 16, 0, 0);
        const float* gC = bcb + (r0 + (lane >> 2)) * 32 + 16 + (lane & 3) * 4;
        float* lC = &Ctl[buf][0][0] + lane * 4;
        __builtin_amdgcn_global_load_lds((const __attribute__((address_space(1))) unsigned int*)gC,
                                         (__attribute__((address_space(3))) unsigned int*)lC, 16, 0, 0);
      }
    } else {
      if (wv == 0) {
        const __hip_bfloat16* g = u_po + (r0 + (lane >> 2)) * D_INNER + dbase + (lane & 3) * 8;
        __hip_bfloat16* l_ = &dut[buf][0][0] + lane * 8;
        __builtin_amdgcn_global_load_lds((const __attribute__((address_space(1))) unsigned int*)g,
                                         (__attribute__((address_space(3))) unsigned int*)l_, 16, 0, 0);
      } else {
        const float* gB = bcb + (r0 + (lane >> 2)) * 32 + (lane & 3) * 4;
        float* lB = &Btl[buf][0][0] + lane * 4;
        __builtin_amdgcn_global_load_lds((const __attribute__((address_space(1))) unsigned int*)gB,
                                         (__attribute__((address_space(3))) unsigned int*)lB, 16, 0, 0);
      }
    }
  };

  auto sprep = [&](int buf, float dtn) {
    #pragma unroll
    for (int i = 0; i < 2; ++i) {
      int idx = tid + 128 * i;
      int row = idx >> 4, n = idx & 15;
      float dv = __shfl(dtn, row);
      float a  = aexp[n];
      st[buf][row][n] = 1.0f / fmaf(dv * dv, a, 1.0f);
    }
  };

  stage(0, 0);
  float dtn = 0.f;
  if (lane < 16) dtn = dtT[(size_t)h * ROWS + rowbase + lane];
  __syncthreads();
  if (tid < 16) dtt[0][tid] = dtn;
  sprep(0, dtn);
  __syncthreads();

  f32x2 w2[2], ys2[2];
  if constexpr (PHASE == 1) {
    #pragma unroll
    for (int k = 0; k < 2; ++k) { w2[k] = (f32x2){0.f, 0.f}; ys2[k] = (f32x2){0.f, 0.f}; }
  } else {
    #pragma unroll
    for (int k = 0; k < 2; ++k)
      #pragma unroll
      for (int j = 0; j < 2; ++j) {
        size_t i2 = (((size_t)bh * NCH + ch) * 64 + dl) * 16 + (n0 + 2 * k + j);
        float2 s = *(const float2*)&states[i2 * 2];
        w2[k][j] = s.x; ys2[k][j] = s.y;
      }
  }
  int cur = 0;

  for (int t = 0; t < TPC; ++t) {
    if (t + 1 < TPC) {
      stage(t + 1, cur ^ 1);
      if (lane < 16) dtn = dtT[(size_t)h * ROWS + rowbase + (size_t)(t + 1) * T_TILE + lane];
    }
    #pragma unroll 4
    for (int l = 0; l < T_TILE; ++l) {
      float uv  = __bfloat162float(dut[cur][l][dwv]);
      float dtv = dtt[cur][l];
      f32x4 Sv4 = *(const f32x4*)&st [cur][l][n0];
      f32x4 Bv4 = *(const f32x4*)&Btl[cur][l][n0];
      float du = dtv * uv;
      f32x2 S2[2] = { {Sv4[0], Sv4[1]}, {Sv4[2], Sv4[3]} };
      f32x2 B2[2] = { {Bv4[0], Bv4[1]}, {Bv4[2], Bv4[3]} };
      if constexpr (PHASE == 3) {
        f32x4 Cv4 = *(const f32x4*)&Ctl[cur][l][n0];
        f32x2 C2[2] = { {Cv4[0], Cv4[1]}, {Cv4[2], Cv4[3]} };
        f32x2 o2 = {0.f, 0.f};
        #pragma unroll
        for (int k = 0; k < 2; ++k) {
          f32x2 dtA = dtv * A2[k];
          f32x2 tmp = w2[k] - dtA * ys2[k];
          tmp = tmp + du * B2[k];
          w2[k] = S2[k] * tmp;
          ys2[k] = ys2[k] + dtv * w2[k];
          o2 = o2 + ys2[k] * C2[k];
        }
        float o = o2[0] + o2[1];
        float ofin = (ng == 0) ? fmaf(Dh, uv, o) : o;
        opart[l][dwv][ng] = ofin;
      } else {
        #pragma unroll
        for (int k = 0; k < 2; ++k) {
          f32x2 dtA = dtv * A2[k];
          f32x2 tmp = w2[k] - dtA * ys2[k];
          tmp = tmp + du * B2[k];
          w2[k] = S2[k] * tmp;
          ys2[k] = ys2[k] + dtv * w2[k];
        }
      }
    }
    if constexpr (PHASE == 3) {
      #pragma unroll
      for (int i = 0; i < 4; ++i) {
        int l  = (lane >> 4) + 4 * i;
        int dd = wv * 16 + d16;
        f32x4 op = *(const f32x4*)&opart[l][dd][0];
        float zv = __bfloat162float(zt[cur][l][dd]);
        float yv = (op[0] + op[1]) + (op[2] + op[3]);
        u_po[(rowbase + (size_t)t * T_TILE + l) * D_INNER + dbase + dd] =
            __float2bfloat16(yv * siluf(zv));
      }
    }
    __syncthreads();
    if (t + 1 < TPC) {
      if (tid < 16) dtt[cur ^ 1][tid] = dtn;
      sprep(cur ^ 1, dtn);
      __syncthreads();
    }
    cur ^= 1;
  }

  if constexpr (PHASE == 1) {
    #pragma unroll
    for (int k = 0; k < 2; ++k)
      #pragma unroll
      for (int j = 0; j < 2; ++j) {
        size_t i2 = (((size_t)bh * NCH + ch) * 64 + dl) * 16 + (n0 + 2 * k + j);
        *(float2*)&states[i2 * 2] = make_float2(w2[k][j], ys2[k][j]);
      }
  }
}

// ---------------------------------------------------------------- launch
extern "C" void kernel_launch(void* const* d_in, const int* in_sizes, int n_in,
                              void* d_out, int out_size, void* d_ws, size_t ws_size,
                              hipStream_t stream) {
  const float* x     = (const float*)d_in[0];
  const float* n1w   = (const float*)d_in[1];
  const float* wi    = (const float*)d_in[2];
  const float* cw    = (const float*)d_in[3];
  const float* cb    = (const float*)d_in[4];
  const float* A_log = (const float*)d_in[5];
  const float* dtb   = (const float*)d_in[6];
  const float* Dp    = (const float*)d_in[7];
  const float* wo    = (const float*)d_in[8];
  const float* n2w   = (const float*)d_in[9];
  const float* wg    = (const float*)d_in[10];
  const float* wu    = (const float*)d_in[11];
  const float* wd    = (const float*)d_in[12];
  float* out = (float*)d_out;

  char* p = (char*)d_ws;
  auto take = [&](size_t b) { char* q = p; p += (b + 255) & ~(size_t)255; return q; };
  __hip_bfloat16* wbi  = (__hip_bfloat16*)take((size_t)ZX_N * D_MODEL * 2);
  __hip_bfloat16* wbo  = (__hip_bfloat16*)take((size_t)D_MODEL * D_INNER * 2);
  __hip_bfloat16* wgu  = (__hip_bfloat16*)take((size_t)GU_N * D_MODEL * 2);
  __hip_bfloat16* wbd  = (__hip_bfloat16*)take((size_t)D_MODEL * FFN_DIM * 2);
  __hip_bfloat16* h0b  = (__hip_bfloat16*)take((size_t)ROWS * D_MODEL * 2);
  char*           region = take((size_t)84 * 1024 * 1024);
  float*          bcb  = (float*)take((size_t)ROWS * 32 * 4);
  float*          bcraw= (float*)take((size_t)ROWS * 32 * 4);
  float*          dtT  = (float*)take((size_t)ROWS * 32 * 4);
  __hip_bfloat16* po   = (__hip_bfloat16*)take((size_t)ROWS * D_INNER * 2);
  float*          pend = (float*)take((size_t)128 * NCH * 64 * 16 * 2 * 4);
  float*          sini = (float*)take((size_t)128 * NCH * 64 * 16 * 2 * 4);
  float*          Pm   = (float*)take((size_t)128 * NCH * 16 * 4 * 4);
  float*          h0f  = (float*)region;
  __hip_bfloat16* zxb  = (__hip_bfloat16*)region;
  float*          h    = (float*)region;
  __hip_bfloat16* gact = (__hip_bfloat16*)(region + 33554432);

  hipFuncSetAttribute(reinterpret_cast<const void*>(&gemm8<5>), hipFuncAttributeMaxDynamicSharedMemorySize, 131072);
  hipFuncSetAttribute(reinterpret_cast<const void*>(&gemmT<4>), hipFuncAttributeMaxDynamicSharedMemorySize, 49152);
  hipFuncSetAttribute(reinterpret_cast<const void*>(&gemmT<1>), hipFuncAttributeMaxDynamicSharedMemorySize, 49152);

  // all weight conversions in one dispatch
  cvtall_k<<<(Z1 + Z2 + Z3 + Z4 + 255) / 256, 256, 0, stream>>>(wi, wo, wg, wu, wd,
                                                                wbi, wbo, wgu, wbd);

  // mixer
  rmsnorm_k<<<ROWS, 256, 0, stream>>>(x, n1w, h0b, h0f);
  vecproj_k<<<ROWS / 4, 256, 0, stream>>>(h0f, wi, dtb, dtT, bcraw);
  gemm8<5><<<(ROWS / 256) * (ZX_N / 256), 512, 131072, stream>>>(h0b, wbi, zxb,
                                                                 ROWS, ZX_N, D_MODEL);
  duconv_k<<<ROWS * 512 / 256, 256, 0, stream>>>(zxb, cw, cb, po);
  bcdt_k<<<ROWS / 8, 256, 0, stream>>>(bcraw, cw, cb, bcb);
  pk_k<<<BATCH * N_HEADS, 256, 0, stream>>>(dtT, A_log, Pm);
  scan_k<1><<<BATCH * N_HEADS * NCH * 2, 128, 0, stream>>>(zxb, bcb, dtT, A_log, Dp, pend, po);
  prop_k<<<BATCH * N_HEADS * 64 * 16 / 256, 256, 0, stream>>>(Pm, pend, sini);
  scan_k<3><<<BATCH * N_HEADS * NCH * 2, 128, 0, stream>>>(zxb, bcb, dtT, A_log, Dp, sini, po);
  gemmT<1><<<(ROWS / 256) * (D_MODEL / 128), 512, 49152, stream>>>(po, wbo, nullptr, h, x,
                                                                   ROWS, D_MODEL, D_INNER);
  // FFN
  rmsnorm_k<<<ROWS, 256, 0, stream>>>(h, n2w, h0b, nullptr);
  gemmT<4><<<(ROWS / 256) * (GU_N / 128), 512, 49152, stream>>>(h0b, wgu, gact, nullptr, nullptr,
                                                                ROWS, GU_N, D_MODEL);
  gemmT<1><<<(ROWS / 256) * (D_MODEL / 128), 512, 49152, stream>>>(gact, wbd, nullptr, out, h,
                                                                   ROWS, D_MODEL, FFN_DIM);
}

// Round 18
// 615.745 us; speedup vs baseline: 3.2441x; 3.2441x over previous
//
#include <hip/hip_runtime.h>
#include <hip/hip_bf16.h>

#define D_MODEL   1024
#define D_STATE   16
#define D_HEAD    64
#define D_CONV    4
#define FFN_DIM   2816
#define D_INNER   2048
#define N_HEADS   32
#define BATCH     4
#define SEQ       2048
#define ROWS      (BATCH*SEQ)     // 8192
#define PROJ_DIM  4160
#define ZX_N      4096            // z + x only
#define CH        128             // scan chunk length
#define NCH       (SEQ/CH)        // 16 chunks
#define GU_N      5632            // 2*FFN_DIM interleaved (44 tiles of 128)

typedef __bf16 bf16x8 __attribute__((ext_vector_type(8)));
typedef float  f32x4  __attribute__((ext_vector_type(4)));
typedef float  f32x2  __attribute__((ext_vector_type(2)));

__device__ __forceinline__ float siluf(float x) { return x / (1.0f + __expf(-x)); }

#define SBAR() do { asm volatile("" ::: "memory"); __builtin_amdgcn_s_barrier(); asm volatile("" ::: "memory"); } while (0)
#define LGKM0() asm volatile("s_waitcnt lgkmcnt(0)" ::: "memory")
#define VMCNT4() asm volatile("s_waitcnt vmcnt(4)" ::: "memory")
#define VMCNT2() asm volatile("s_waitcnt vmcnt(2)" ::: "memory")
#define VMCNT0() asm volatile("s_waitcnt vmcnt(0)" ::: "memory")

// ---------------------------------------------------------------- all weight conversions in ONE dispatch
#define Z1 (ZX_N * D_MODEL)
#define Z2 (D_MODEL * D_INNER)
#define Z3 (GU_N * D_MODEL)
#define Z4 (D_MODEL * FFN_DIM)
__global__ void cvtall_k(const float* __restrict__ wi, const float* __restrict__ wo,
                         const float* __restrict__ wg, const float* __restrict__ wu,
                         const float* __restrict__ wd,
                         __hip_bfloat16* __restrict__ wbi, __hip_bfloat16* __restrict__ wbo,
                         __hip_bfloat16* __restrict__ wgu, __hip_bfloat16* __restrict__ wbd) {
  int i = blockIdx.x * blockDim.x + threadIdx.x;
  if (i < Z1) {
    wbi[i] = __float2bfloat16(wi[i]);
  } else if (i < Z1 + Z2) {
    int j = i - Z1;
    wbo[j] = __float2bfloat16(wo[j]);
  } else if (i < Z1 + Z2 + Z3) {
    int j = i - Z1 - Z2;
    int r = j >> 10, c = j & 1023;
    int tile = r >> 7, rr = r & 127;
    const float* src = (rr < 64)
        ? wg + (size_t)(tile * 64 + rr) * D_MODEL + c
        : wu + (size_t)(tile * 64 + (rr - 64)) * D_MODEL + c;
    wgu[j] = __float2bfloat16(*src);
  } else if (i < Z1 + Z2 + Z3 + Z4) {
    int j = i - Z1 - Z2 - Z3;
    wbd[j] = __float2bfloat16(wd[j]);
  }
}

// ---------------------------------------------------------------- rmsnorm
__global__ __launch_bounds__(256) void rmsnorm_k(const float* __restrict__ x,
                                                 const float* __restrict__ w,
                                                 __hip_bfloat16* __restrict__ out,
                                                 float* __restrict__ outf) {
  int row = blockIdx.x;
  int t = threadIdx.x;
  const float* xr = x + (size_t)row * D_MODEL;
  float4 v = ((const float4*)xr)[t];
  float ss = v.x*v.x + v.y*v.y + v.z*v.z + v.w*v.w;
  #pragma unroll
  for (int o = 32; o > 0; o >>= 1) ss += __shfl_xor(ss, o);
  __shared__ float red[4];
  if ((t & 63) == 0) red[t >> 6] = ss;
  __syncthreads();
  ss = red[0] + red[1] + red[2] + red[3];
  float scale = rsqrtf(ss * (1.0f / D_MODEL) + 1e-6f);
  float4 wv = ((const float4*)w)[t];
  float4 r;
  r.x = v.x * scale * wv.x; r.y = v.y * scale * wv.y;
  r.z = v.z * scale * wv.z; r.w = v.w * scale * wv.w;
  __hip_bfloat16* orow = out + (size_t)row * D_MODEL + t * 4;
  orow[0] = __float2bfloat16(r.x);
  orow[1] = __float2bfloat16(r.y);
  orow[2] = __float2bfloat16(r.z);
  orow[3] = __float2bfloat16(r.w);
  if (outf) ((float4*)(outf + (size_t)row * D_MODEL))[t] = r;
}

// ---------------------------------------------------------------- dt + B/C projection (pure f32, block-per-4-rows)
__global__ __launch_bounds__(256) void vecproj_k(const float* __restrict__ xn,
                                                 const float* __restrict__ wi,
                                                 const float* __restrict__ dtb,
                                                 float* __restrict__ dtT,
                                                 float* __restrict__ bcraw) {
  const int r0 = blockIdx.x * 4;
  const int t  = threadIdx.x;
  const int o   = t >> 2;
  const int seg = t & 3;

  __shared__ float xs[4][D_MODEL];
  #pragma unroll
  for (int i = 0; i < 4; ++i)
    ((float4*)&xs[i][0])[t] = ((const float4*)(xn + (size_t)(r0 + i) * D_MODEL))[t];
  __syncthreads();

  const int wrow = (o < 32) ? (2 * D_INNER + o) : (2 * D_INNER + 2 * D_STATE + (o - 32));
  const float4* w4 = (const float4*)(wi + (size_t)wrow * D_MODEL) + seg * 64;
  const float4* x0 = (const float4*)&xs[0][0] + seg * 64;
  const float4* x1 = (const float4*)&xs[1][0] + seg * 64;
  const float4* x2 = (const float4*)&xs[2][0] + seg * 64;
  const float4* x3 = (const float4*)&xs[3][0] + seg * 64;
  float a0 = 0.f, a1 = 0.f, a2 = 0.f, a3 = 0.f;
  #pragma unroll 8
  for (int k = 0; k < 64; ++k) {
    float4 wv = w4[k];
    float4 v0 = x0[k], v1 = x1[k], v2 = x2[k], v3 = x3[k];
    a0 = fmaf(wv.x, v0.x, fmaf(wv.y, v0.y, fmaf(wv.z, v0.z, fmaf(wv.w, v0.w, a0))));
    a1 = fmaf(wv.x, v1.x, fmaf(wv.y, v1.y, fmaf(wv.z, v1.z, fmaf(wv.w, v1.w, a1))));
    a2 = fmaf(wv.x, v2.x, fmaf(wv.y, v2.y, fmaf(wv.z, v2.z, fmaf(wv.w, v2.w, a2))));
    a3 = fmaf(wv.x, v3.x, fmaf(wv.y, v3.y, fmaf(wv.z, v3.z, fmaf(wv.w, v3.w, a3))));
  }
  #pragma unroll
  for (int m = 1; m < 4; m <<= 1) {
    a0 += __shfl_xor(a0, m);
    a1 += __shfl_xor(a1, m);
    a2 += __shfl_xor(a2, m);
    a3 += __shfl_xor(a3, m);
  }
  if (seg == 0) {
    float v[4] = {a0, a1, a2, a3};
    if (o < 32) {
      #pragma unroll
      for (int i = 0; i < 4; ++i) bcraw[(size_t)(r0 + i) * 32 + o] = v[i];
    } else {
      int hh = o - 32;
      float bias = dtb[hh];
      #pragma unroll
      for (int i = 0; i < 4; ++i) {
        float xv = v[i] + bias;
        dtT[(size_t)hh * ROWS + r0 + i] = (xv > 20.f) ? xv : log1pf(__expf(xv));
      }
    }
  }
}

// ---------------------------------------------------------------- 256x256 8-phase GEMM (counted vmcnt)
// EPI: 5 plain bf16 store.
template<int EPI>
__global__ __launch_bounds__(512, 2) void gemm8(
    const __hip_bfloat16* __restrict__ A,
    const __hip_bfloat16* __restrict__ Bw,
    __hip_bfloat16* __restrict__ Cb,
    int M, int N, int K)
{
  extern __shared__ char lds[];
  const int nwg = (M >> 8) * (N >> 8);
  int bid = blockIdx.x;
  bid = (bid & 7) * (nwg >> 3) + (bid >> 3);
  const int ntn = N >> 8;
  const int bm = (bid / ntn) << 8;
  const int bn = (bid % ntn) << 8;

  const int tid  = threadIdx.x;
  const int wid  = tid >> 6;
  const int lane = tid & 63;
  const int wm = wid >> 2;
  const int wn = wid & 3;
  const int r16 = lane & 15;
  const int kg  = lane >> 4;

  const int rb = ((r16 << 6) + (kg << 4)) ^ ((r16 & 8) << 2);

  const int s_sub = tid >> 6;
  const int s_w   = (tid & 63) << 4;
  const int s_wp  = s_w ^ ((((s_w) >> 9) & 1) << 5);
  const int s_row = ((s_sub >> 1) << 4) + (s_wp >> 6);
  const int s_col = ((s_sub & 1) << 5) + ((s_wp >> 1) & 31);

  auto stage = [&](int buf, int mat, int half, int c, int kt) {
    const __hip_bfloat16* src = (mat == 0)
        ? A  + (size_t)(bm + half * 128 + c * 64 + s_row) * K + kt * 64 + s_col
        : Bw + (size_t)(bn + half * 128 + c * 64 + s_row) * K + kt * 64 + s_col;
    char* dst = lds + buf * 65536 + mat * 32768 + half * 16384 + c * 8192 + tid * 16;
    __builtin_amdgcn_global_load_lds((const __attribute__((address_space(1))) unsigned int*)src,
                                     (__attribute__((address_space(3))) unsigned int*)dst,
                                     16, 0, 0);
  };

  f32x4 acc[8][4] = {};
  bf16x8 af[4][2], bfr[4][2];

  const int NT = K >> 6;
  stage(0,0,0,0,0); stage(0,0,0,1,0); stage(0,0,1,0,0); stage(0,0,1,1,0);
  stage(0,1,0,0,0); stage(0,1,0,1,0); stage(0,1,1,0,0); stage(0,1,1,1,0);
  __syncthreads();

  for (int kt = 0; kt < NT; ++kt) {
    const int buf = kt & 1, nbuf = buf ^ 1;
    const bool st = (kt + 1 < NT);
    const char* Ab = lds + buf * 65536 + wm * 16384;
    const char* Bb = lds + buf * 65536 + 32768 + (wn >> 1) * 16384 + (wn & 1) * 8192;

    #pragma unroll
    for (int mi2 = 0; mi2 < 4; ++mi2)
      #pragma unroll
      for (int kk = 0; kk < 2; ++kk)
        af[mi2][kk] = *(const bf16x8*)(Ab + (mi2 * 2 + kk) * 1024 + rb);
    #pragma unroll
    for (int ni = 0; ni < 2; ++ni)
      #pragma unroll
      for (int kk = 0; kk < 2; ++kk)
        bfr[ni][kk] = *(const bf16x8*)(Bb + (ni * 2 + kk) * 1024 + rb);
    if (st) { stage(nbuf,1,0,0,kt+1); stage(nbuf,1,0,1,kt+1); }
    SBAR(); LGKM0();
    __builtin_amdgcn_s_setprio(1);
    #pragma unroll
    for (int mi2 = 0; mi2 < 4; ++mi2)
      #pragma unroll
      for (int ni = 0; ni < 2; ++ni)
        #pragma unroll
        for (int kk = 0; kk < 2; ++kk)
          acc[mi2][ni] = __builtin_amdgcn_mfma_f32_16x16x32_bf16(af[mi2][kk], bfr[ni][kk], acc[mi2][ni], 0, 0, 0);
    __builtin_amdgcn_s_setprio(0);
    SBAR();

    #pragma unroll
    for (int ni = 2; ni < 4; ++ni)
      #pragma unroll
      for (int kk = 0; kk < 2; ++kk)
        bfr[ni][kk] = *(const bf16x8*)(Bb + (ni * 2 + kk) * 1024 + rb);
    if (st) { stage(nbuf,1,1,0,kt+1); stage(nbuf,1,1,1,kt+1); }
    SBAR(); LGKM0();
    __builtin_amdgcn_s_setprio(1);
    #pragma unroll
    for (int mi2 = 0; mi2 < 4; ++mi2)
      #pragma unroll
      for (int ni = 2; ni < 4; ++ni)
        #pragma unroll
        for (int kk = 0; kk < 2; ++kk)
          acc[mi2][ni] = __builtin_amdgcn_mfma_f32_16x16x32_bf16(af[mi2][kk], bfr[ni][kk], acc[mi2][ni], 0, 0, 0);
    __builtin_amdgcn_s_setprio(0);
    if (st) { VMCNT4(); } else { VMCNT0(); }
    SBAR();

    #pragma unroll
    for (int mi2 = 0; mi2 < 4; ++mi2)
      #pragma unroll
      for (int kk = 0; kk < 2; ++kk)
        af[mi2][kk] = *(const bf16x8*)(Ab + ((4 + mi2) * 2 + kk) * 1024 + rb);
    if (st) { stage(nbuf,0,0,0,kt+1); stage(nbuf,0,1,0,kt+1); }
    SBAR(); LGKM0();
    __builtin_amdgcn_s_setprio(1);
    #pragma unroll
    for (int mi2 = 0; mi2 < 4; ++mi2)
      #pragma unroll
      for (int ni = 0; ni < 2; ++ni)
        #pragma unroll
        for (int kk = 0; kk < 2; ++kk)
          acc[4 + mi2][ni] = __builtin_amdgcn_mfma_f32_16x16x32_bf16(af[mi2][kk], bfr[ni][kk], acc[4 + mi2][ni], 0, 0, 0);
    __builtin_amdgcn_s_setprio(0);
    SBAR();

    if (st) { stage(nbuf,0,0,1,kt+1); stage(nbuf,0,1,1,kt+1); }
    SBAR(); LGKM0();
    __builtin_amdgcn_s_setprio(1);
    #pragma unroll
    for (int mi2 = 0; mi2 < 4; ++mi2)
      #pragma unroll
      for (int ni = 2; ni < 4; ++ni)
        #pragma unroll
        for (int kk = 0; kk < 2; ++kk)
          acc[4 + mi2][ni] = __builtin_amdgcn_mfma_f32_16x16x32_bf16(af[mi2][kk], bfr[ni][kk], acc[4 + mi2][ni], 0, 0, 0);
    __builtin_amdgcn_s_setprio(0);
    VMCNT2();
    SBAR();
  }

  #pragma unroll
  for (int mi = 0; mi < 8; ++mi) {
    #pragma unroll
    for (int ni = 0; ni < 4; ++ni) {
      #pragma unroll
      for (int j = 0; j < 4; ++j) {
        int r = bm + wm * 128 + mi * 16 + kg * 4 + j;
        int c = bn + wn * 64 + ni * 16 + r16;
        Cb[(size_t)r * N + c] = __float2bfloat16(acc[mi][ni][j]);
      }
    }
  }
}

// ---------------------------------------------------------------- 256x128 BK=32 GEMM, 2-deep, 2 blocks/CU
// EPI: 4 fused gate/up (bf16 LDS exchange, silu(g)*u); 1 f32 store + add_src.
template<int EPI>
__global__ __launch_bounds__(512, 4) void gemmT(
    const __hip_bfloat16* __restrict__ A,
    const __hip_bfloat16* __restrict__ Bw,
    __hip_bfloat16* __restrict__ Cb,
    float* __restrict__ Cf,
    const float* __restrict__ add_src,
    int M, int N, int K)
{
  extern __shared__ char lds[];          // 49152
  const int nwg = (M >> 8) * (N >> 7);
  int bid = blockIdx.x;
  bid = (bid & 7) * (nwg >> 3) + (bid >> 3);
  const int ntn = N >> 7;
  const int bm = (bid / ntn) << 8;
  const int bn = (bid % ntn) << 7;

  const int tid  = threadIdx.x;
  const int wid  = tid >> 6;
  const int lane = tid & 63;
  const int wm = wid >> 1;          // 0..3
  const int wn = wid & 1;           // 0..1
  const int r16 = lane & 15;
  const int kg  = lane >> 4;

  const int rb = ((r16 << 6) + (kg << 4)) ^ ((r16 & 8) << 2);

  const int s_sub = tid >> 6;
  const int s_w   = (tid & 63) << 4;
  const int s_wp  = s_w ^ ((((s_w) >> 9) & 1) << 5);
  const int s_row = (s_sub << 4) + (s_wp >> 6);
  const int s_col = (s_wp >> 1) & 31;

  auto stageA = [&](int buf, int h, int kt) {
    const __hip_bfloat16* src = A + (size_t)(bm + h * 128 + s_row) * K + kt * 32 + s_col;
    char* dst = lds + buf * 24576 + h * 8192 + tid * 16;
    __builtin_amdgcn_global_load_lds((const __attribute__((address_space(1))) unsigned int*)src,
                                     (__attribute__((address_space(3))) unsigned int*)dst,
                                     16, 0, 0);
  };
  auto stageB = [&](int buf, int kt) {
    const __hip_bfloat16* src = Bw + (size_t)(bn + s_row) * K + kt * 32 + s_col;
    char* dst = lds + buf * 24576 + 16384 + tid * 16;
    __builtin_amdgcn_global_load_lds((const __attribute__((address_space(1))) unsigned int*)src,
                                     (__attribute__((address_space(3))) unsigned int*)dst,
                                     16, 0, 0);
  };

  f32x4 acc[4][4] = {};

  const int NT = K >> 5;
  stageA(0, 0, 0); stageA(0, 1, 0); stageB(0, 0);
  __syncthreads();

  for (int kt = 0; kt < NT; ++kt) {
    const int buf = kt & 1, nbuf = buf ^ 1;
    const bool st = (kt + 1 < NT);
    const char* Ab = lds + buf * 24576 + wm * 4096;
    const char* Bb = lds + buf * 24576 + 16384 + wn * 4096;

    bf16x8 af[4], bfr[4];
    #pragma unroll
    for (int mi = 0; mi < 4; ++mi) af[mi]  = *(const bf16x8*)(Ab + mi * 1024 + rb);
    #pragma unroll
    for (int ni = 0; ni < 4; ++ni) bfr[ni] = *(const bf16x8*)(Bb + ni * 1024 + rb);
    if (st) { stageA(nbuf, 0, kt + 1); stageA(nbuf, 1, kt + 1); stageB(nbuf, kt + 1); }
    __builtin_amdgcn_s_setprio(1);
    #pragma unroll
    for (int mi = 0; mi < 4; ++mi)
      #pragma unroll
      for (int ni = 0; ni < 4; ++ni)
        acc[mi][ni] = __builtin_amdgcn_mfma_f32_16x16x32_bf16(af[mi], bfr[ni], acc[mi][ni], 0, 0, 0);
    __builtin_amdgcn_s_setprio(0);
    VMCNT0();
    SBAR();
  }

  if constexpr (EPI == 4) {
    __hip_bfloat16* xch = (__hip_bfloat16*)lds;   // [256][72] bf16
    __syncthreads();
    if (wn == 0) {
      #pragma unroll
      for (int mi = 0; mi < 4; ++mi)
        #pragma unroll
        for (int ni = 0; ni < 4; ++ni)
          #pragma unroll
          for (int j = 0; j < 4; ++j) {
            int row = wm * 64 + mi * 16 + kg * 4 + j;
            int col = ni * 16 + r16;
            xch[row * 72 + col] = __float2bfloat16(siluf(acc[mi][ni][j]));
          }
    }
    __syncthreads();
    if (wn == 1) {
      #pragma unroll
      for (int mi = 0; mi < 4; ++mi)
        #pragma unroll
        for (int ni = 0; ni < 4; ++ni)
          #pragma unroll
          for (int j = 0; j < 4; ++j) {
            int row = wm * 64 + mi * 16 + kg * 4 + j;
            int col = ni * 16 + r16;
            float g = __bfloat162float(xch[row * 72 + col]);
            Cb[(size_t)(bm + row) * FFN_DIM + (bn >> 1) + col] =
                __float2bfloat16(g * acc[mi][ni][j]);
          }
    }
  } else if constexpr (EPI == 1) {
    #pragma unroll
    for (int mi = 0; mi < 4; ++mi)
      #pragma unroll
      for (int ni = 0; ni < 4; ++ni)
        #pragma unroll
        for (int j = 0; j < 4; ++j) {
          int r = bm + wm * 64 + mi * 16 + kg * 4 + j;
          int c = bn + wn * 64 + ni * 16 + r16;
          size_t idx = (size_t)r * N + c;
          Cf[idx] = acc[mi][ni][j] + add_src[idx];
        }
  } else {
    #pragma unroll
    for (int mi = 0; mi < 4; ++mi)
      #pragma unroll
      for (int ni = 0; ni < 4; ++ni)
        #pragma unroll
        for (int j = 0; j < 4; ++j) {
          int r = bm + wm * 64 + mi * 16 + kg * 4 + j;
          int c = bn + wn * 64 + ni * 16 + r16;
          Cb[(size_t)r * N + c] = __float2bfloat16(acc[mi][ni][j]);
        }
  }
}

// ---------------------------------------------------------------- u = silu(depthwise conv(x)), x in bf16, u bf16 -> po
__global__ __launch_bounds__(256) void duconv_k(const __hip_bfloat16* __restrict__ zxb,
                                                const float* __restrict__ cw,
                                                const float* __restrict__ cb,
                                                __hip_bfloat16* __restrict__ u_po) {
  int idx = blockIdx.x * 256 + threadIdx.x;
  int q = idx & 511;
  int r = idx >> 9;
  int d0 = q << 2;
  int l = r & (SEQ - 1);
  float4 cb4 = ((const float4*)cb)[q];
  float tw[4][4];
  #pragma unroll
  for (int i = 0; i < 4; ++i) {
    float4 t = ((const float4*)cw)[d0 + i];
    tw[i][0] = t.x; tw[i][1] = t.y; tw[i][2] = t.z; tw[i][3] = t.w;
  }
  float a[4] = {cb4.x, cb4.y, cb4.z, cb4.w};
  #pragma unroll
  for (int k = 0; k < 4; ++k) {
    if (l - 3 + k >= 0) {
      union { ushort4 u4; __hip_bfloat16 b[4]; } R;
      R.u4 = *(const ushort4*)(zxb + (size_t)(r - 3 + k) * ZX_N + D_INNER + d0);
      a[0] = fmaf(__bfloat162float(R.b[0]), tw[0][k], a[0]);
      a[1] = fmaf(__bfloat162float(R.b[1]), tw[1][k], a[1]);
      a[2] = fmaf(__bfloat162float(R.b[2]), tw[2][k], a[2]);
      a[3] = fmaf(__bfloat162float(R.b[3]), tw[3][k], a[3]);
    }
  }
  union { ushort4 u4; __hip_bfloat16 b[4]; } pk;
  #pragma unroll
  for (int i = 0; i < 4; ++i) pk.b[i] = __float2bfloat16(siluf(a[i]));
  *(ushort4*)(u_po + (size_t)r * D_INNER + d0) = pk.u4;
}

// ---------------------------------------------------------------- conv+silu+normalize for the 32 B/C channels
__global__ __launch_bounds__(256) void bcdt_k(const float* __restrict__ bcraw,
                                              const float* __restrict__ cw,
                                              const float* __restrict__ cb,
                                              float* __restrict__ bc) {
  int t = threadIdx.x;
  int r = blockIdx.x * 8 + (t >> 5);
  int ch = t & 31;
  int l = r & (SEQ - 1);
  int c = D_INNER + ch;
  float acc = cb[c];
  #pragma unroll
  for (int k = 0; k < 4; ++k) {
    int lp = l - 3 + k;
    if (lp >= 0)
      acc = fmaf(bcraw[(size_t)(r - 3 + k) * 32 + ch], cw[c * 4 + k], acc);
  }
  acc = siluf(acc);
  float ss = acc * acc;
  ss += __shfl_xor(ss, 1);
  ss += __shfl_xor(ss, 2);
  ss += __shfl_xor(ss, 4);
  ss += __shfl_xor(ss, 8);
  bc[r * 32 + ch] = acc / (sqrtf(ss) + 1e-6f);
}

// ---------------------------------------------------------------- chunk transfer matrices
__global__ __launch_bounds__(256) void pk_k(const float* __restrict__ dtT,
                                            const float* __restrict__ A_log,
                                            float* __restrict__ Pm) {
  int bh = blockIdx.x;
  int h = bh & 31;
  int t = threadIdx.x;
  int ch = t >> 4, n = t & 15;
  float a = __expf(A_log[h * 16 + n]);
  const float* dtp = dtT + (size_t)h * ROWS + (size_t)(bh >> 5) * SEQ + ch * CH;
  float p00 = 1.f, p01 = 0.f, p10 = 0.f, p11 = 1.f;
  for (int l = 0; l < CH; ++l) {
    float dt = dtp[l];
    float s  = 1.0f / fmaf(dt * dt, a, 1.0f);
    float m00 = s;
    float m01 = -dt * a * s;
    float m10 = dt * s;
    float m11 = fmaf(-dt * a, m10, 1.0f);
    float q00 = fmaf(m00, p00, m01 * p10);
    float q01 = fmaf(m00, p01, m01 * p11);
    float q10 = fmaf(m10, p00, m11 * p10);
    float q11 = fmaf(m10, p01, m11 * p11);
    p00 = q00; p01 = q01; p10 = q10; p11 = q11;
  }
  float4 v = {p00, p01, p10, p11};
  *(float4*)&Pm[(((size_t)bh * NCH + ch) * 16 + n) * 4] = v;
}

// ---------------------------------------------------------------- propagate chunk-boundary states
__global__ __launch_bounds__(256) void prop_k(const float* __restrict__ Pm,
                                              const float* __restrict__ pend,
                                              float* __restrict__ sinit) {
  int gid = blockIdx.x * 256 + threadIdx.x;
  int n  = gid & 15;
  int d  = (gid >> 4) & 63;
  int bh = gid >> 10;
  float s0 = 0.f, s1 = 0.f;
  for (int c = 0; c < NCH; ++c) {
    size_t i2 = (((size_t)bh * NCH + c) * 64 + d) * 16 + n;
    *(float2*)&sinit[i2 * 2] = make_float2(s0, s1);
    float4 P  = *(const float4*)&Pm[(((size_t)bh * NCH + c) * 16 + n) * 4];
    float2 pe = *(const float2*)&pend[i2 * 2];
    float t0 = fmaf(P.x, s0, fmaf(P.y, s1, pe.x));
    float t1 = fmaf(P.z, s0, fmaf(P.w, s1, pe.y));
    s0 = t0; s1 = t1;
  }
}

// ---------------------------------------------------------------- chunked scan (u precomputed, f32x2 packed recurrence)
#define T_TILE 16
#define TPC (CH / T_TILE)
template<int PHASE>
__global__ __launch_bounds__(128) void scan_k(
    const __hip_bfloat16* __restrict__ zxb, const float* __restrict__ bcb,
    const float* __restrict__ dtT, const float* __restrict__ A_log,
    const float* __restrict__ Dp, float* __restrict__ states,
    __hip_bfloat16* u_po)
{
  const int blk  = blockIdx.x;
  const int half = blk & 1;
  const int ch   = (blk >> 1) & 15;
  const int h    = (blk >> 5) & 31;
  const int b    = blk >> 10;
  const int bh   = b * 32 + h;
  const int tid  = threadIdx.x;
  const int wv   = tid >> 6;
  const int lane = tid & 63;
  const int d16  = lane & 15;
  const int ng   = lane >> 4;
  const int n0   = ng * 4;
  const int dwv  = wv * 16 + d16;
  const int dl   = half * 32 + dwv;
  const int dbase = h * 64 + half * 32;
  const size_t rowbase = (size_t)b * SEQ + (size_t)ch * CH;

  __shared__ __hip_bfloat16 dut[2][T_TILE][32];
  __shared__ float Btl[2][T_TILE][16];
  __shared__ float Ctl[PHASE == 3 ? 2 : 1][T_TILE][16];
  __shared__ __hip_bfloat16 zt [PHASE == 3 ? 2 : 1][T_TILE][32];
  __shared__ float st [2][T_TILE][16];
  __shared__ float dtt[2][T_TILE];
  __shared__ float aexp[16];
  __shared__ float opart[PHASE == 3 ? T_TILE : 1][32][4];

  if (tid < 16) aexp[tid] = __expf(A_log[h * 16 + tid]);

  f32x2 A2[2];
  #pragma unroll
  for (int k = 0; k < 2; ++k) {
    A2[k][0] = __expf(A_log[h * 16 + n0 + 2 * k]);
    A2[k][1] = __expf(A_log[h * 16 + n0 + 2 * k + 1]);
  }
  const float Dh = Dp[h];

  auto stage = [&](int tile, int buf) {
    const size_t r0 = rowbase + (size_t)tile * T_TILE;
    if constexpr (PHASE == 3) {
      if (wv == 0) {
        const __hip_bfloat16* g = u_po + (r0 + (lane >> 2)) * D_INNER + dbase + (lane & 3) * 8;
        __hip_bfloat16* l_ = &dut[buf][0][0] + lane * 8;
        __builtin_amdgcn_global_load_lds((const __attribute__((address_space(1))) unsigned int*)g,
                                         (__attribute__((address_space(3))) unsigned int*)l_, 16, 0, 0);
      } else {
        const __hip_bfloat16* gz = zxb + (r0 + (lane >> 2)) * ZX_N + dbase + (lane & 3) * 8;
        __hip_bfloat16* lz = &zt[buf][0][0] + lane * 8;
        __builtin_amdgcn_global_load_lds((const __attribute__((address_space(1))) unsigned int*)gz,
                                         (__attribute__((address_space(3))) unsigned int*)lz, 16, 0, 0);
        const float* gB = bcb + (r0 + (lane >> 2)) * 32 + (lane & 3) * 4;
        float* lB = &Btl[buf][0][0] + lane * 4;
        __builtin_amdgcn_global_load_lds((const __attribute__((address_space(1))) unsigned int*)gB,
                                         (__attribute__((address_space(3))) unsigned int*)lB, 16, 0, 0);
        const float* gC = bcb + (r0 + (lane >> 2)) * 32 + 16 + (lane & 3) * 4;
        float* lC = &Ctl[buf][0][0] + lane * 4;
        __builtin_amdgcn_global_load_lds((const __attribute__((address_space(1))) unsigned int*)gC,
                                         (__attribute__((address_space(3))) unsigned int*)lC, 16, 0, 0);
      }
    } else {
      if (wv == 0) {
        const __hip_bfloat16* g = u_po + (r0 + (lane >> 2)) * D_INNER + dbase + (lane & 3) * 8;
        __hip_bfloat16* l_ = &dut[buf][0][0] + lane * 8;
        __builtin_amdgcn_global_load_lds((const __attribute__((address_space(1))) unsigned int*)g,
                                         (__attribute__((address_space(3))) unsigned int*)l_, 16, 0, 0);
      } else {
        const float* gB = bcb + (r0 + (lane >> 2)) * 32 + (lane & 3) * 4;
        float* lB = &Btl[buf][0][0] + lane * 4;
        __builtin_amdgcn_global_load_lds((const __attribute__((address_space(1))) unsigned int*)gB,
                                         (__attribute__((address_space(3))) unsigned int*)lB, 16, 0, 0);
      }
    }
  };

  auto sprep = [&](int buf, float dtn) {
    #pragma unroll
    for (int i = 0; i < 2; ++i) {
      int idx = tid + 128 * i;
      int row = idx >> 4, n = idx & 15;
      float dv = __shfl(dtn, row);
      float a  = aexp[n];
      st[buf][row][n] = 1.0f / fmaf(dv * dv, a, 1.0f);
    }
  };

  stage(0, 0);
  float dtn = 0.f;
  if (lane < 16) dtn = dtT[(size_t)h * ROWS + rowbase + lane];
  __syncthreads();
  if (tid < 16) dtt[0][tid] = dtn;
  sprep(0, dtn);
  __syncthreads();

  f32x2 w2[2], ys2[2];
  if constexpr (PHASE == 1) {
    #pragma unroll
    for (int k = 0; k < 2; ++k) { w2[k] = (f32x2){0.f, 0.f}; ys2[k] = (f32x2){0.f, 0.f}; }
  } else {
    #pragma unroll
    for (int k = 0; k < 2; ++k)
      #pragma unroll
      for (int j = 0; j < 2; ++j) {
        size_t i2 = (((size_t)bh * NCH + ch) * 64 + dl) * 16 + (n0 + 2 * k + j);
        float2 s = *(const float2*)&states[i2 * 2];
        w2[k][j] = s.x; ys2[k][j] = s.y;
      }
  }
  int cur = 0;

  for (int t = 0; t < TPC; ++t) {
    if (t + 1 < TPC) {
      stage(t + 1, cur ^ 1);
      if (lane < 16) dtn = dtT[(size_t)h * ROWS + rowbase + (size_t)(t + 1) * T_TILE + lane];
    }
    #pragma unroll 4
    for (int l = 0; l < T_TILE; ++l) {
      float uv  = __bfloat162float(dut[cur][l][dwv]);
      float dtv = dtt[cur][l];
      f32x4 Sv4 = *(const f32x4*)&st [cur][l][n0];
      f32x4 Bv4 = *(const f32x4*)&Btl[cur][l][n0];
      float du = dtv * uv;
      f32x2 S2[2] = { {Sv4[0], Sv4[1]}, {Sv4[2], Sv4[3]} };
      f32x2 B2[2] = { {Bv4[0], Bv4[1]}, {Bv4[2], Bv4[3]} };
      if constexpr (PHASE == 3) {
        f32x4 Cv4 = *(const f32x4*)&Ctl[cur][l][n0];
        f32x2 C2[2] = { {Cv4[0], Cv4[1]}, {Cv4[2], Cv4[3]} };
        f32x2 o2 = {0.f, 0.f};
        #pragma unroll
        for (int k = 0; k < 2; ++k) {
          f32x2 dtA = dtv * A2[k];
          f32x2 tmp = w2[k] - dtA * ys2[k];
          tmp = tmp + du * B2[k];
          w2[k] = S2[k] * tmp;
          ys2[k] = ys2[k] + dtv * w2[k];
          o2 = o2 + ys2[k] * C2[k];
        }
        float o = o2[0] + o2[1];
        float ofin = (ng == 0) ? fmaf(Dh, uv, o) : o;
        opart[l][dwv][ng] = ofin;
      } else {
        #pragma unroll
        for (int k = 0; k < 2; ++k) {
          f32x2 dtA = dtv * A2[k];
          f32x2 tmp = w2[k] - dtA * ys2[k];
          tmp = tmp + du * B2[k];
          w2[k] = S2[k] * tmp;
          ys2[k] = ys2[k] + dtv * w2[k];
        }
      }
    }
    if constexpr (PHASE == 3) {
      #pragma unroll
      for (int i = 0; i < 4; ++i) {
        int l  = (lane >> 4) + 4 * i;
        int dd = wv * 16 + d16;
        f32x4 op = *(const f32x4*)&opart[l][dd][0];
        float zv = __bfloat162float(zt[cur][l][dd]);
        float yv = (op[0] + op[1]) + (op[2] + op[3]);
        u_po[(rowbase + (size_t)t * T_TILE + l) * D_INNER + dbase + dd] =
            __float2bfloat16(yv * siluf(zv));
      }
    }
    __syncthreads();
    if (t + 1 < TPC) {
      if (tid < 16) dtt[cur ^ 1][tid] = dtn;
      sprep(cur ^ 1, dtn);
      __syncthreads();
    }
    cur ^= 1;
  }

  if constexpr (PHASE == 1) {
    #pragma unroll
    for (int k = 0; k < 2; ++k)
      #pragma unroll
      for (int j = 0; j < 2; ++j) {
        size_t i2 = (((size_t)bh * NCH + ch) * 64 + dl) * 16 + (n0 + 2 * k + j);
        *(float2*)&states[i2 * 2] = make_float2(w2[k][j], ys2[k][j]);
      }
  }
}

// ---------------------------------------------------------------- launch
extern "C" void kernel_launch(void* const* d_in, const int* in_sizes, int n_in,
                              void* d_out, int out_size, void* d_ws, size_t ws_size,
                              hipStream_t stream) {
  const float* x     = (const float*)d_in[0];
  const float* n1w   = (const float*)d_in[1];
  const float* wi    = (const float*)d_in[2];
  const float* cw    = (const float*)d_in[3];
  const float* cb    = (const float*)d_in[4];
  const float* A_log = (const float*)d_in[5];
  const float* dtb   = (const float*)d_in[6];
  const float* Dp    = (const float*)d_in[7];
  const float* wo    = (const float*)d_in[8];
  const float* n2w   = (const float*)d_in[9];
  const float* wg    = (const float*)d_in[10];
  const float* wu    = (const float*)d_in[11];
  const float* wd    = (const float*)d_in[12];
  float* out = (float*)d_out;

  char* p = (char*)d_ws;
  auto take = [&](size_t b) { char* q = p; p += (b + 255) & ~(size_t)255; return q; };
  __hip_bfloat16* wbi  = (__hip_bfloat16*)take((size_t)ZX_N * D_MODEL * 2);
  __hip_bfloat16* wbo  = (__hip_bfloat16*)take((size_t)D_MODEL * D_INNER * 2);
  __hip_bfloat16* wgu  = (__hip_bfloat16*)take((size_t)GU_N * D_MODEL * 2);
  __hip_bfloat16* wbd  = (__hip_bfloat16*)take((size_t)D_MODEL * FFN_DIM * 2);
  __hip_bfloat16* h0b  = (__hip_bfloat16*)take((size_t)ROWS * D_MODEL * 2);
  char*           region = take((size_t)84 * 1024 * 1024);
  float*          bcb  = (float*)take((size_t)ROWS * 32 * 4);
  float*          bcraw= (float*)take((size_t)ROWS * 32 * 4);
  float*          dtT  = (float*)take((size_t)ROWS * 32 * 4);
  __hip_bfloat16* po   = (__hip_bfloat16*)take((size_t)ROWS * D_INNER * 2);
  float*          pend = (float*)take((size_t)128 * NCH * 64 * 16 * 2 * 4);
  float*          sini = (float*)take((size_t)128 * NCH * 64 * 16 * 2 * 4);
  float*          Pm   = (float*)take((size_t)128 * NCH * 16 * 4 * 4);
  float*          h0f  = (float*)region;
  __hip_bfloat16* zxb  = (__hip_bfloat16*)region;
  float*          h    = (float*)region;
  __hip_bfloat16* gact = (__hip_bfloat16*)(region + 33554432);

  hipFuncSetAttribute(reinterpret_cast<const void*>(&gemm8<5>), hipFuncAttributeMaxDynamicSharedMemorySize, 131072);
  hipFuncSetAttribute(reinterpret_cast<const void*>(&gemmT<4>), hipFuncAttributeMaxDynamicSharedMemorySize, 49152);
  hipFuncSetAttribute(reinterpret_cast<const void*>(&gemmT<1>), hipFuncAttributeMaxDynamicSharedMemorySize, 49152);

  // all weight conversions in one dispatch
  cvtall_k<<<(Z1 + Z2 + Z3 + Z4 + 255) / 256, 256, 0, stream>>>(wi, wo, wg, wu, wd,
                                                                wbi, wbo, wgu, wbd);

  // mixer
  rmsnorm_k<<<ROWS, 256, 0, stream>>>(x, n1w, h0b, h0f);
  vecproj_k<<<ROWS / 4, 256, 0, stream>>>(h0f, wi, dtb, dtT, bcraw);
  gemm8<5><<<(ROWS / 256) * (ZX_N / 256), 512, 131072, stream>>>(h0b, wbi, zxb,
                                                                 ROWS, ZX_N, D_MODEL);
  duconv_k<<<ROWS * 512 / 256, 256, 0, stream>>>(zxb, cw, cb, po);
  bcdt_k<<<ROWS / 8, 256, 0, stream>>>(bcraw, cw, cb, bcb);
  pk_k<<<BATCH * N_HEADS, 256, 0, stream>>>(dtT, A_log, Pm);
  scan_k<1><<<BATCH * N_HEADS * NCH * 2, 128, 0, stream>>>(zxb, bcb, dtT, A_log, Dp, pend, po);
  prop_k<<<BATCH * N_HEADS * 64 * 16 / 256, 256, 0, stream>>>(Pm, pend, sini);
  scan_k<3><<<BATCH * N_HEADS * NCH * 2, 128, 0, stream>>>(zxb, bcb, dtT, A_log, Dp, sini, po);
  gemmT<1><<<(ROWS / 256) * (D_MODEL / 128), 512, 49152, stream>>>(po, wbo, nullptr, h, x,
                                                                   ROWS, D_MODEL, D_INNER);
  // FFN
  rmsnorm_k<<<ROWS, 256, 0, stream>>>(h, n2w, h0b, nullptr);
  gemmT<4><<<(ROWS / 256) * (GU_N / 128), 512, 49152, stream>>>(h0b, wgu, gact, nullptr, nullptr,
                                                                ROWS, GU_N, D_MODEL);
  gemmT<1><<<(ROWS / 256) * (D_MODEL / 128), 512, 49152, stream>>>(gact, wbd, nullptr, out, h,
                                                                   ROWS, D_MODEL, FFN_DIM);
}

// Round 19
// 598.415 us; speedup vs baseline: 3.3380x; 1.0290x over previous
//
#include <hip/hip_runtime.h>
#include <hip/hip_bf16.h>

#define D_MODEL   1024
#define D_STATE   16
#define D_HEAD    64
#define D_CONV    4
#define FFN_DIM   2816
#define D_INNER   2048
#define N_HEADS   32
#define BATCH     4
#define SEQ       2048
#define ROWS      (BATCH*SEQ)     // 8192
#define PROJ_DIM  4160
#define ZX_N      4096            // z + x only
#define CH        128             // scan chunk length
#define NCH       (SEQ/CH)        // 16 chunks
#define GU_N      5632            // 2*FFN_DIM interleaved (44 tiles of 128)

typedef __bf16 bf16x8 __attribute__((ext_vector_type(8)));
typedef float  f32x4  __attribute__((ext_vector_type(4)));
typedef float  f32x2  __attribute__((ext_vector_type(2)));

__device__ __forceinline__ float siluf(float x) { return x / (1.0f + __expf(-x)); }

#define SBAR() do { asm volatile("" ::: "memory"); __builtin_amdgcn_s_barrier(); asm volatile("" ::: "memory"); } while (0)
#define LGKM0() asm volatile("s_waitcnt lgkmcnt(0)" ::: "memory")
#define VMCNT4() asm volatile("s_waitcnt vmcnt(4)" ::: "memory")
#define VMCNT2() asm volatile("s_waitcnt vmcnt(2)" ::: "memory")
#define VMCNT0() asm volatile("s_waitcnt vmcnt(0)" ::: "memory")

// ---------------------------------------------------------------- all weight conversions in ONE dispatch
#define Z1 (ZX_N * D_MODEL)
#define Z2 (D_MODEL * D_INNER)
#define Z3 (GU_N * D_MODEL)
#define Z4 (D_MODEL * FFN_DIM)
__global__ void cvtall_k(const float* __restrict__ wi, const float* __restrict__ wo,
                         const float* __restrict__ wg, const float* __restrict__ wu,
                         const float* __restrict__ wd,
                         __hip_bfloat16* __restrict__ wbi, __hip_bfloat16* __restrict__ wbo,
                         __hip_bfloat16* __restrict__ wgu, __hip_bfloat16* __restrict__ wbd) {
  int i = blockIdx.x * blockDim.x + threadIdx.x;
  if (i < Z1) {
    wbi[i] = __float2bfloat16(wi[i]);
  } else if (i < Z1 + Z2) {
    int j = i - Z1;
    wbo[j] = __float2bfloat16(wo[j]);
  } else if (i < Z1 + Z2 + Z3) {
    int j = i - Z1 - Z2;
    int r = j >> 10, c = j & 1023;
    int tile = r >> 7, rr = r & 127;
    const float* src = (rr < 64)
        ? wg + (size_t)(tile * 64 + rr) * D_MODEL + c
        : wu + (size_t)(tile * 64 + (rr - 64)) * D_MODEL + c;
    wgu[j] = __float2bfloat16(*src);
  } else if (i < Z1 + Z2 + Z3 + Z4) {
    int j = i - Z1 - Z2 - Z3;
    wbd[j] = __float2bfloat16(wd[j]);
  }
}

// ---------------------------------------------------------------- rmsnorm
__global__ __launch_bounds__(256) void rmsnorm_k(const float* __restrict__ x,
                                                 const float* __restrict__ w,
                                                 __hip_bfloat16* __restrict__ out,
                                                 float* __restrict__ outf) {
  int row = blockIdx.x;
  int t = threadIdx.x;
  const float* xr = x + (size_t)row * D_MODEL;
  float4 v = ((const float4*)xr)[t];
  float ss = v.x*v.x + v.y*v.y + v.z*v.z + v.w*v.w;
  #pragma unroll
  for (int o = 32; o > 0; o >>= 1) ss += __shfl_xor(ss, o);
  __shared__ float red[4];
  if ((t & 63) == 0) red[t >> 6] = ss;
  __syncthreads();
  ss = red[0] + red[1] + red[2] + red[3];
  float scale = rsqrtf(ss * (1.0f / D_MODEL) + 1e-6f);
  float4 wv = ((const float4*)w)[t];
  float4 r;
  r.x = v.x * scale * wv.x; r.y = v.y * scale * wv.y;
  r.z = v.z * scale * wv.z; r.w = v.w * scale * wv.w;
  __hip_bfloat16* orow = out + (size_t)row * D_MODEL + t * 4;
  orow[0] = __float2bfloat16(r.x);
  orow[1] = __float2bfloat16(r.y);
  orow[2] = __float2bfloat16(r.z);
  orow[3] = __float2bfloat16(r.w);
  if (outf) ((float4*)(outf + (size_t)row * D_MODEL))[t] = r;
}

// ---------------------------------------------------------------- dt + B/C projection (pure f32, block-per-4-rows)
__global__ __launch_bounds__(256) void vecproj_k(const float* __restrict__ xn,
                                                 const float* __restrict__ wi,
                                                 const float* __restrict__ dtb,
                                                 float* __restrict__ dtT,
                                                 float* __restrict__ bcraw) {
  const int r0 = blockIdx.x * 4;
  const int t  = threadIdx.x;
  const int o   = t >> 2;
  const int seg = t & 3;

  __shared__ float xs[4][D_MODEL];
  #pragma unroll
  for (int i = 0; i < 4; ++i)
    ((float4*)&xs[i][0])[t] = ((const float4*)(xn + (size_t)(r0 + i) * D_MODEL))[t];
  __syncthreads();

  const int wrow = (o < 32) ? (2 * D_INNER + o) : (2 * D_INNER + 2 * D_STATE + (o - 32));
  const float4* w4 = (const float4*)(wi + (size_t)wrow * D_MODEL) + seg * 64;
  const float4* x0 = (const float4*)&xs[0][0] + seg * 64;
  const float4* x1 = (const float4*)&xs[1][0] + seg * 64;
  const float4* x2 = (const float4*)&xs[2][0] + seg * 64;
  const float4* x3 = (const float4*)&xs[3][0] + seg * 64;
  float a0 = 0.f, a1 = 0.f, a2 = 0.f, a3 = 0.f;
  #pragma unroll 8
  for (int k = 0; k < 64; ++k) {
    float4 wv = w4[k];
    float4 v0 = x0[k], v1 = x1[k], v2 = x2[k], v3 = x3[k];
    a0 = fmaf(wv.x, v0.x, fmaf(wv.y, v0.y, fmaf(wv.z, v0.z, fmaf(wv.w, v0.w, a0))));
    a1 = fmaf(wv.x, v1.x, fmaf(wv.y, v1.y, fmaf(wv.z, v1.z, fmaf(wv.w, v1.w, a1))));
    a2 = fmaf(wv.x, v2.x, fmaf(wv.y, v2.y, fmaf(wv.z, v2.z, fmaf(wv.w, v2.w, a2))));
    a3 = fmaf(wv.x, v3.x, fmaf(wv.y, v3.y, fmaf(wv.z, v3.z, fmaf(wv.w, v3.w, a3))));
  }
  #pragma unroll
  for (int m = 1; m < 4; m <<= 1) {
    a0 += __shfl_xor(a0, m);
    a1 += __shfl_xor(a1, m);
    a2 += __shfl_xor(a2, m);
    a3 += __shfl_xor(a3, m);
  }
  if (seg == 0) {
    float v[4] = {a0, a1, a2, a3};
    if (o < 32) {
      #pragma unroll
      for (int i = 0; i < 4; ++i) bcraw[(size_t)(r0 + i) * 32 + o] = v[i];
    } else {
      int hh = o - 32;
      float bias = dtb[hh];
      #pragma unroll
      for (int i = 0; i < 4; ++i) {
        float xv = v[i] + bias;
        dtT[(size_t)hh * ROWS + r0 + i] = (xv > 20.f) ? xv : log1pf(__expf(xv));
      }
    }
  }
}

// ---------------------------------------------------------------- 256x256 8-phase GEMM (counted vmcnt)
// EPI: 5 plain bf16 store.
template<int EPI>
__global__ __launch_bounds__(512, 2) void gemm8(
    const __hip_bfloat16* __restrict__ A,
    const __hip_bfloat16* __restrict__ Bw,
    __hip_bfloat16* __restrict__ Cb,
    int M, int N, int K)
{
  extern __shared__ char lds[];
  const int nwg = (M >> 8) * (N >> 8);
  int bid = blockIdx.x;
  bid = (bid & 7) * (nwg >> 3) + (bid >> 3);
  const int ntn = N >> 8;
  const int bm = (bid / ntn) << 8;
  const int bn = (bid % ntn) << 8;

  const int tid  = threadIdx.x;
  const int wid  = tid >> 6;
  const int lane = tid & 63;
  const int wm = wid >> 2;
  const int wn = wid & 3;
  const int r16 = lane & 15;
  const int kg  = lane >> 4;

  const int rb = ((r16 << 6) + (kg << 4)) ^ ((r16 & 8) << 2);

  const int s_sub = tid >> 6;
  const int s_w   = (tid & 63) << 4;
  const int s_wp  = s_w ^ ((((s_w) >> 9) & 1) << 5);
  const int s_row = ((s_sub >> 1) << 4) + (s_wp >> 6);
  const int s_col = ((s_sub & 1) << 5) + ((s_wp >> 1) & 31);

  auto stage = [&](int buf, int mat, int half, int c, int kt) {
    const __hip_bfloat16* src = (mat == 0)
        ? A  + (size_t)(bm + half * 128 + c * 64 + s_row) * K + kt * 64 + s_col
        : Bw + (size_t)(bn + half * 128 + c * 64 + s_row) * K + kt * 64 + s_col;
    char* dst = lds + buf * 65536 + mat * 32768 + half * 16384 + c * 8192 + tid * 16;
    __builtin_amdgcn_global_load_lds((const __attribute__((address_space(1))) unsigned int*)src,
                                     (__attribute__((address_space(3))) unsigned int*)dst,
                                     16, 0, 0);
  };

  f32x4 acc[8][4] = {};
  bf16x8 af[4][2], bfr[4][2];

  const int NT = K >> 6;
  stage(0,0,0,0,0); stage(0,0,0,1,0); stage(0,0,1,0,0); stage(0,0,1,1,0);
  stage(0,1,0,0,0); stage(0,1,0,1,0); stage(0,1,1,0,0); stage(0,1,1,1,0);
  __syncthreads();

  for (int kt = 0; kt < NT; ++kt) {
    const int buf = kt & 1, nbuf = buf ^ 1;
    const bool st = (kt + 1 < NT);
    const char* Ab = lds + buf * 65536 + wm * 16384;
    const char* Bb = lds + buf * 65536 + 32768 + (wn >> 1) * 16384 + (wn & 1) * 8192;

    #pragma unroll
    for (int mi2 = 0; mi2 < 4; ++mi2)
      #pragma unroll
      for (int kk = 0; kk < 2; ++kk)
        af[mi2][kk] = *(const bf16x8*)(Ab + (mi2 * 2 + kk) * 1024 + rb);
    #pragma unroll
    for (int ni = 0; ni < 2; ++ni)
      #pragma unroll
      for (int kk = 0; kk < 2; ++kk)
        bfr[ni][kk] = *(const bf16x8*)(Bb + (ni * 2 + kk) * 1024 + rb);
    if (st) { stage(nbuf,1,0,0,kt+1); stage(nbuf,1,0,1,kt+1); }
    SBAR(); LGKM0();
    __builtin_amdgcn_s_setprio(1);
    #pragma unroll
    for (int mi2 = 0; mi2 < 4; ++mi2)
      #pragma unroll
      for (int ni = 0; ni < 2; ++ni)
        #pragma unroll
        for (int kk = 0; kk < 2; ++kk)
          acc[mi2][ni] = __builtin_amdgcn_mfma_f32_16x16x32_bf16(af[mi2][kk], bfr[ni][kk], acc[mi2][ni], 0, 0, 0);
    __builtin_amdgcn_s_setprio(0);
    SBAR();

    #pragma unroll
    for (int ni = 2; ni < 4; ++ni)
      #pragma unroll
      for (int kk = 0; kk < 2; ++kk)
        bfr[ni][kk] = *(const bf16x8*)(Bb + (ni * 2 + kk) * 1024 + rb);
    if (st) { stage(nbuf,1,1,0,kt+1); stage(nbuf,1,1,1,kt+1); }
    SBAR(); LGKM0();
    __builtin_amdgcn_s_setprio(1);
    #pragma unroll
    for (int mi2 = 0; mi2 < 4; ++mi2)
      #pragma unroll
      for (int ni = 2; ni < 4; ++ni)
        #pragma unroll
        for (int kk = 0; kk < 2; ++kk)
          acc[mi2][ni] = __builtin_amdgcn_mfma_f32_16x16x32_bf16(af[mi2][kk], bfr[ni][kk], acc[mi2][ni], 0, 0, 0);
    __builtin_amdgcn_s_setprio(0);
    if (st) { VMCNT4(); } else { VMCNT0(); }
    SBAR();

    #pragma unroll
    for (int mi2 = 0; mi2 < 4; ++mi2)
      #pragma unroll
      for (int kk = 0; kk < 2; ++kk)
        af[mi2][kk] = *(const bf16x8*)(Ab + ((4 + mi2) * 2 + kk) * 1024 + rb);
    if (st) { stage(nbuf,0,0,0,kt+1); stage(nbuf,0,1,0,kt+1); }
    SBAR(); LGKM0();
    __builtin_amdgcn_s_setprio(1);
    #pragma unroll
    for (int mi2 = 0; mi2 < 4; ++mi2)
      #pragma unroll
      for (int ni = 0; ni < 2; ++ni)
        #pragma unroll
        for (int kk = 0; kk < 2; ++kk)
          acc[4 + mi2][ni] = __builtin_amdgcn_mfma_f32_16x16x32_bf16(af[mi2][kk], bfr[ni][kk], acc[4 + mi2][ni], 0, 0, 0);
    __builtin_amdgcn_s_setprio(0);
    SBAR();

    if (st) { stage(nbuf,0,0,1,kt+1); stage(nbuf,0,1,1,kt+1); }
    SBAR(); LGKM0();
    __builtin_amdgcn_s_setprio(1);
    #pragma unroll
    for (int mi2 = 0; mi2 < 4; ++mi2)
      #pragma unroll
      for (int ni = 2; ni < 4; ++ni)
        #pragma unroll
        for (int kk = 0; kk < 2; ++kk)
          acc[4 + mi2][ni] = __builtin_amdgcn_mfma_f32_16x16x32_bf16(af[mi2][kk], bfr[ni][kk], acc[4 + mi2][ni], 0, 0, 0);
    __builtin_amdgcn_s_setprio(0);
    VMCNT2();
    SBAR();
  }

  #pragma unroll
  for (int mi = 0; mi < 8; ++mi) {
    #pragma unroll
    for (int ni = 0; ni < 4; ++ni) {
      #pragma unroll
      for (int j = 0; j < 4; ++j) {
        int r = bm + wm * 128 + mi * 16 + kg * 4 + j;
        int c = bn + wn * 64 + ni * 16 + r16;
        Cb[(size_t)r * N + c] = __float2bfloat16(acc[mi][ni][j]);
      }
    }
  }
}

// ---------------------------------------------------------------- 256x128 BK=32 GEMM, 2-deep, 2 blocks/CU (fused gate/up)
template<int EPI>
__global__ __launch_bounds__(512, 4) void gemmT(
    const __hip_bfloat16* __restrict__ A,
    const __hip_bfloat16* __restrict__ Bw,
    __hip_bfloat16* __restrict__ Cb,
    int M, int N, int K)
{
  extern __shared__ char lds[];          // 49152
  const int nwg = (M >> 8) * (N >> 7);
  int bid = blockIdx.x;
  bid = (bid & 7) * (nwg >> 3) + (bid >> 3);
  const int ntn = N >> 7;
  const int bm = (bid / ntn) << 8;
  const int bn = (bid % ntn) << 7;

  const int tid  = threadIdx.x;
  const int wid  = tid >> 6;
  const int lane = tid & 63;
  const int wm = wid >> 1;          // 0..3
  const int wn = wid & 1;           // 0..1
  const int r16 = lane & 15;
  const int kg  = lane >> 4;

  const int rb = ((r16 << 6) + (kg << 4)) ^ ((r16 & 8) << 2);

  const int s_sub = tid >> 6;
  const int s_w   = (tid & 63) << 4;
  const int s_wp  = s_w ^ ((((s_w) >> 9) & 1) << 5);
  const int s_row = (s_sub << 4) + (s_wp >> 6);
  const int s_col = (s_wp >> 1) & 31;

  auto stageA = [&](int buf, int h, int kt) {
    const __hip_bfloat16* src = A + (size_t)(bm + h * 128 + s_row) * K + kt * 32 + s_col;
    char* dst = lds + buf * 24576 + h * 8192 + tid * 16;
    __builtin_amdgcn_global_load_lds((const __attribute__((address_space(1))) unsigned int*)src,
                                     (__attribute__((address_space(3))) unsigned int*)dst,
                                     16, 0, 0);
  };
  auto stageB = [&](int buf, int kt) {
    const __hip_bfloat16* src = Bw + (size_t)(bn + s_row) * K + kt * 32 + s_col;
    char* dst = lds + buf * 24576 + 16384 + tid * 16;
    __builtin_amdgcn_global_load_lds((const __attribute__((address_space(1))) unsigned int*)src,
                                     (__attribute__((address_space(3))) unsigned int*)dst,
                                     16, 0, 0);
  };

  f32x4 acc[4][4] = {};

  const int NT = K >> 5;
  stageA(0, 0, 0); stageA(0, 1, 0); stageB(0, 0);
  __syncthreads();

  for (int kt = 0; kt < NT; ++kt) {
    const int buf = kt & 1, nbuf = buf ^ 1;
    const bool st = (kt + 1 < NT);
    const char* Ab = lds + buf * 24576 + wm * 4096;
    const char* Bb = lds + buf * 24576 + 16384 + wn * 4096;

    bf16x8 af[4], bfr[4];
    #pragma unroll
    for (int mi = 0; mi < 4; ++mi) af[mi]  = *(const bf16x8*)(Ab + mi * 1024 + rb);
    #pragma unroll
    for (int ni = 0; ni < 4; ++ni) bfr[ni] = *(const bf16x8*)(Bb + ni * 1024 + rb);
    if (st) { stageA(nbuf, 0, kt + 1); stageA(nbuf, 1, kt + 1); stageB(nbuf, kt + 1); }
    __builtin_amdgcn_s_setprio(1);
    #pragma unroll
    for (int mi = 0; mi < 4; ++mi)
      #pragma unroll
      for (int ni = 0; ni < 4; ++ni)
        acc[mi][ni] = __builtin_amdgcn_mfma_f32_16x16x32_bf16(af[mi], bfr[ni], acc[mi][ni], 0, 0, 0);
    __builtin_amdgcn_s_setprio(0);
    VMCNT0();
    SBAR();
  }

  if constexpr (EPI == 4) {
    __hip_bfloat16* xch = (__hip_bfloat16*)lds;   // [256][72] bf16
    __syncthreads();
    if (wn == 0) {
      #pragma unroll
      for (int mi = 0; mi < 4; ++mi)
        #pragma unroll
        for (int ni = 0; ni < 4; ++ni)
          #pragma unroll
          for (int j = 0; j < 4; ++j) {
            int row = wm * 64 + mi * 16 + kg * 4 + j;
            int col = ni * 16 + r16;
            xch[row * 72 + col] = __float2bfloat16(siluf(acc[mi][ni][j]));
          }
    }
    __syncthreads();
    if (wn == 1) {
      #pragma unroll
      for (int mi = 0; mi < 4; ++mi)
        #pragma unroll
        for (int ni = 0; ni < 4; ++ni)
          #pragma unroll
          for (int j = 0; j < 4; ++j) {
            int row = wm * 64 + mi * 16 + kg * 4 + j;
            int col = ni * 16 + r16;
            float g = __bfloat162float(xch[row * 72 + col]);
            Cb[(size_t)(bm + row) * FFN_DIM + (bn >> 1) + col] =
                __float2bfloat16(g * acc[mi][ni][j]);
          }
    }
  } else {
    #pragma unroll
    for (int mi = 0; mi < 4; ++mi)
      #pragma unroll
      for (int ni = 0; ni < 4; ++ni)
        #pragma unroll
        for (int j = 0; j < 4; ++j) {
          int r = bm + wm * 64 + mi * 16 + kg * 4 + j;
          int c = bn + wn * 64 + ni * 16 + r16;
          Cb[(size_t)r * N + c] = __float2bfloat16(acc[mi][ni][j]);
        }
  }
}

// ---------------------------------------------------------------- 256x128 8-phase GEMM (N=1024, counted vmcnt)
template<int EPI>
__global__ __launch_bounds__(512, 2) void gemm8B(
    const __hip_bfloat16* __restrict__ A,
    const __hip_bfloat16* __restrict__ Bw,
    float* __restrict__ Cf,
    __hip_bfloat16* __restrict__ Cb,
    const float* __restrict__ add_src,
    int M, int N, int K)
{
  extern __shared__ char lds[];
  const int nwg = (M >> 8) * (N >> 7);
  int bid = blockIdx.x;
  bid = (bid & 7) * (nwg >> 3) + (bid >> 3);
  const int ntn = N >> 7;
  const int bm = (bid / ntn) << 8;
  const int bn = (bid % ntn) << 7;

  const int tid  = threadIdx.x;
  const int wid  = tid >> 6;
  const int lane = tid & 63;
  const int wm = wid >> 2;
  const int wn = wid & 3;
  const int r16 = lane & 15;
  const int kg  = lane >> 4;

  const int rb = ((r16 << 6) + (kg << 4)) ^ ((r16 & 8) << 2);

  const int s_sub = tid >> 6;
  const int s_w   = (tid & 63) << 4;
  const int s_wp  = s_w ^ ((((s_w) >> 9) & 1) << 5);
  const int s_row = ((s_sub >> 1) << 4) + (s_wp >> 6);
  const int s_col = ((s_sub & 1) << 5) + ((s_wp >> 1) & 31);

  auto stageA = [&](int buf, int half, int c, int kt) {
    const __hip_bfloat16* src = A + (size_t)(bm + half * 128 + c * 64 + s_row) * K + kt * 64 + s_col;
    char* dst = lds + buf * 65536 + half * 16384 + c * 8192 + tid * 16;
    __builtin_amdgcn_global_load_lds((const __attribute__((address_space(1))) unsigned int*)src,
                                     (__attribute__((address_space(3))) unsigned int*)dst,
                                     16, 0, 0);
  };
  auto stageB = [&](int buf, int c, int kt) {
    const __hip_bfloat16* src = Bw + (size_t)(bn + c * 64 + s_row) * K + kt * 64 + s_col;
    char* dst = lds + buf * 65536 + 32768 + c * 8192 + tid * 16;
    __builtin_amdgcn_global_load_lds((const __attribute__((address_space(1))) unsigned int*)src,
                                     (__attribute__((address_space(3))) unsigned int*)dst,
                                     16, 0, 0);
  };

  f32x4 acc[8][2] = {};
  bf16x8 af[4][2], bfr[2][2];

  const int NT = K >> 6;
  stageB(0,0,0); stageB(0,1,0);
  stageA(0,0,0,0); stageA(0,1,0,0); stageA(0,0,1,0); stageA(0,1,1,0);
  __syncthreads();

  for (int kt = 0; kt < NT; ++kt) {
    const int buf = kt & 1, nbuf = buf ^ 1;
    const bool st = (kt + 1 < NT);
    const char* Ab = lds + buf * 65536 + wm * 16384;
    const char* Bb = lds + buf * 65536 + 32768 + (wn >> 1) * 8192 + (wn & 1) * 4096;

    #pragma unroll
    for (int mi2 = 0; mi2 < 4; ++mi2)
      #pragma unroll
      for (int kk = 0; kk < 2; ++kk)
        af[mi2][kk] = *(const bf16x8*)(Ab + (mi2 * 2 + kk) * 1024 + rb);
    #pragma unroll
    for (int ni = 0; ni < 2; ++ni)
      #pragma unroll
      for (int kk = 0; kk < 2; ++kk)
        bfr[ni][kk] = *(const bf16x8*)(Bb + (ni * 2 + kk) * 1024 + rb);
    if (st) { stageB(nbuf,0,kt+1); stageB(nbuf,1,kt+1); stageA(nbuf,0,0,kt+1); stageA(nbuf,1,0,kt+1); }
    SBAR(); LGKM0();
    __builtin_amdgcn_s_setprio(1);
    #pragma unroll
    for (int mi2 = 0; mi2 < 4; ++mi2)
      #pragma unroll
      for (int ni = 0; ni < 2; ++ni)
        #pragma unroll
        for (int kk = 0; kk < 2; ++kk)
          acc[mi2][ni] = __builtin_amdgcn_mfma_f32_16x16x32_bf16(af[mi2][kk], bfr[ni][kk], acc[mi2][ni], 0, 0, 0);
    __builtin_amdgcn_s_setprio(0);
    if (st) { VMCNT4(); } else { VMCNT0(); }
    SBAR();

    #pragma unroll
    for (int mi2 = 0; mi2 < 4; ++mi2)
      #pragma unroll
      for (int kk = 0; kk < 2; ++kk)
        af[mi2][kk] = *(const bf16x8*)(Ab + ((4 + mi2) * 2 + kk) * 1024 + rb);
    if (st) { stageA(nbuf,0,1,kt+1); stageA(nbuf,1,1,kt+1); }
    SBAR(); LGKM0();
    __builtin_amdgcn_s_setprio(1);
    #pragma unroll
    for (int mi2 = 0; mi2 < 4; ++mi2)
      #pragma unroll
      for (int ni = 0; ni < 2; ++ni)
        #pragma unroll
        for (int kk = 0; kk < 2; ++kk)
          acc[4 + mi2][ni] = __builtin_amdgcn_mfma_f32_16x16x32_bf16(af[mi2][kk], bfr[ni][kk], acc[4 + mi2][ni], 0, 0, 0);
    __builtin_amdgcn_s_setprio(0);
    VMCNT2();
    SBAR();
  }

  #pragma unroll
  for (int mi = 0; mi < 8; ++mi) {
    #pragma unroll
    for (int ni = 0; ni < 2; ++ni) {
      #pragma unroll
      for (int j = 0; j < 4; ++j) {
        int r = bm + wm * 128 + mi * 16 + kg * 4 + j;
        int c = bn + wn * 32 + ni * 16 + r16;
        size_t idx = (size_t)r * N + c;
        float v = acc[mi][ni][j];
        if constexpr (EPI == 0) {
          Cf[idx] = v;
        } else if constexpr (EPI == 1) {
          Cf[idx] = v + add_src[idx];
        }
      }
    }
  }
}

// ---------------------------------------------------------------- u = silu(depthwise conv(x)), x in bf16, u bf16 -> po
__global__ __launch_bounds__(256) void duconv_k(const __hip_bfloat16* __restrict__ zxb,
                                                const float* __restrict__ cw,
                                                const float* __restrict__ cb,
                                                __hip_bfloat16* __restrict__ u_po) {
  int idx = blockIdx.x * 256 + threadIdx.x;
  int q = idx & 511;
  int r = idx >> 9;
  int d0 = q << 2;
  int l = r & (SEQ - 1);
  float4 cb4 = ((const float4*)cb)[q];
  float tw[4][4];
  #pragma unroll
  for (int i = 0; i < 4; ++i) {
    float4 t = ((const float4*)cw)[d0 + i];
    tw[i][0] = t.x; tw[i][1] = t.y; tw[i][2] = t.z; tw[i][3] = t.w;
  }
  float a[4] = {cb4.x, cb4.y, cb4.z, cb4.w};
  #pragma unroll
  for (int k = 0; k < 4; ++k) {
    if (l - 3 + k >= 0) {
      union { ushort4 u4; __hip_bfloat16 b[4]; } R;
      R.u4 = *(const ushort4*)(zxb + (size_t)(r - 3 + k) * ZX_N + D_INNER + d0);
      a[0] = fmaf(__bfloat162float(R.b[0]), tw[0][k], a[0]);
      a[1] = fmaf(__bfloat162float(R.b[1]), tw[1][k], a[1]);
      a[2] = fmaf(__bfloat162float(R.b[2]), tw[2][k], a[2]);
      a[3] = fmaf(__bfloat162float(R.b[3]), tw[3][k], a[3]);
    }
  }
  union { ushort4 u4; __hip_bfloat16 b[4]; } pk;
  #pragma unroll
  for (int i = 0; i < 4; ++i) pk.b[i] = __float2bfloat16(siluf(a[i]));
  *(ushort4*)(u_po + (size_t)r * D_INNER + d0) = pk.u4;
}

// ---------------------------------------------------------------- conv+silu+normalize for the 32 B/C channels
__global__ __launch_bounds__(256) void bcdt_k(const float* __restrict__ bcraw,
                                              const float* __restrict__ cw,
                                              const float* __restrict__ cb,
                                              float* __restrict__ bc) {
  int t = threadIdx.x;
  int r = blockIdx.x * 8 + (t >> 5);
  int ch = t & 31;
  int l = r & (SEQ - 1);
  int c = D_INNER + ch;
  float acc = cb[c];
  #pragma unroll
  for (int k = 0; k < 4; ++k) {
    int lp = l - 3 + k;
    if (lp >= 0)
      acc = fmaf(bcraw[(size_t)(r - 3 + k) * 32 + ch], cw[c * 4 + k], acc);
  }
  acc = siluf(acc);
  float ss = acc * acc;
  ss += __shfl_xor(ss, 1);
  ss += __shfl_xor(ss, 2);
  ss += __shfl_xor(ss, 4);
  ss += __shfl_xor(ss, 8);
  bc[r * 32 + ch] = acc / (sqrtf(ss) + 1e-6f);
}

// ---------------------------------------------------------------- chunk transfer matrices
__global__ __launch_bounds__(256) void pk_k(const float* __restrict__ dtT,
                                            const float* __restrict__ A_log,
                                            float* __restrict__ Pm) {
  int bh = blockIdx.x;
  int h = bh & 31;
  int t = threadIdx.x;
  int ch = t >> 4, n = t & 15;
  float a = __expf(A_log[h * 16 + n]);
  const float* dtp = dtT + (size_t)h * ROWS + (size_t)(bh >> 5) * SEQ + ch * CH;
  float p00 = 1.f, p01 = 0.f, p10 = 0.f, p11 = 1.f;
  for (int l = 0; l < CH; ++l) {
    float dt = dtp[l];
    float s  = 1.0f / fmaf(dt * dt, a, 1.0f);
    float m00 = s;
    float m01 = -dt * a * s;
    float m10 = dt * s;
    float m11 = fmaf(-dt * a, m10, 1.0f);
    float q00 = fmaf(m00, p00, m01 * p10);
    float q01 = fmaf(m00, p01, m01 * p11);
    float q10 = fmaf(m10, p00, m11 * p10);
    float q11 = fmaf(m10, p01, m11 * p11);
    p00 = q00; p01 = q01; p10 = q10; p11 = q11;
  }
  float4 v = {p00, p01, p10, p11};
  *(float4*)&Pm[(((size_t)bh * NCH + ch) * 16 + n) * 4] = v;
}

// ---------------------------------------------------------------- propagate chunk-boundary states
__global__ __launch_bounds__(256) void prop_k(const float* __restrict__ Pm,
                                              const float* __restrict__ pend,
                                              float* __restrict__ sinit) {
  int gid = blockIdx.x * 256 + threadIdx.x;
  int n  = gid & 15;
  int d  = (gid >> 4) & 63;
  int bh = gid >> 10;
  float s0 = 0.f, s1 = 0.f;
  for (int c = 0; c < NCH; ++c) {
    size_t i2 = (((size_t)bh * NCH + c) * 64 + d) * 16 + n;
    *(float2*)&sinit[i2 * 2] = make_float2(s0, s1);
    float4 P  = *(const float4*)&Pm[(((size_t)bh * NCH + c) * 16 + n) * 4];
    float2 pe = *(const float2*)&pend[i2 * 2];
    float t0 = fmaf(P.x, s0, fmaf(P.y, s1, pe.x));
    float t1 = fmaf(P.z, s0, fmaf(P.w, s1, pe.y));
    s0 = t0; s1 = t1;
  }
}

// ---------------------------------------------------------------- chunked scan (u precomputed, f32x2 packed recurrence)
#define T_TILE 16
#define TPC (CH / T_TILE)
template<int PHASE>
__global__ __launch_bounds__(128) void scan_k(
    const __hip_bfloat16* __restrict__ zxb, const float* __restrict__ bcb,
    const float* __restrict__ dtT, const float* __restrict__ A_log,
    const float* __restrict__ Dp, float* __restrict__ states,
    __hip_bfloat16* u_po)
{
  const int blk  = blockIdx.x;
  const int half = blk & 1;
  const int ch   = (blk >> 1) & 15;
  const int h    = (blk >> 5) & 31;
  const int b    = blk >> 10;
  const int bh   = b * 32 + h;
  const int tid  = threadIdx.x;
  const int wv   = tid >> 6;
  const int lane = tid & 63;
  const int d16  = lane & 15;
  const int ng   = lane >> 4;
  const int n0   = ng * 4;
  const int dwv  = wv * 16 + d16;
  const int dl   = half * 32 + dwv;
  const int dbase = h * 64 + half * 32;
  const size_t rowbase = (size_t)b * SEQ + (size_t)ch * CH;

  __shared__ __hip_bfloat16 dut[2][T_TILE][32];
  __shared__ float Btl[2][T_TILE][16];
  __shared__ float Ctl[PHASE == 3 ? 2 : 1][T_TILE][16];
  __shared__ __hip_bfloat16 zt [PHASE == 3 ? 2 : 1][T_TILE][32];
  __shared__ float st [2][T_TILE][16];
  __shared__ float dtt[2][T_TILE];
  __shared__ float aexp[16];
  __shared__ float opart[PHASE == 3 ? T_TILE : 1][32][4];

  if (tid < 16) aexp[tid] = __expf(A_log[h * 16 + tid]);

  f32x2 A2[2];
  #pragma unroll
  for (int k = 0; k < 2; ++k) {
    A2[k][0] = __expf(A_log[h * 16 + n0 + 2 * k]);
    A2[k][1] = __expf(A_log[h * 16 + n0 + 2 * k + 1]);
  }
  const float Dh = Dp[h];

  auto stage = [&](int tile, int buf) {
    const size_t r0 = rowbase + (size_t)tile * T_TILE;
    if constexpr (PHASE == 3) {
      if (wv == 0) {
        const __hip_bfloat16* g = u_po + (r0 + (lane >> 2)) * D_INNER + dbase + (lane & 3) * 8;
        __hip_bfloat16* l_ = &dut[buf][0][0] + lane * 8;
        __builtin_amdgcn_global_load_lds((const __attribute__((address_space(1))) unsigned int*)g,
                                         (__attribute__((address_space(3))) unsigned int*)l_, 16, 0, 0);
      } else {
        const __hip_bfloat16* gz = zxb + (r0 + (lane >> 2)) * ZX_N + dbase + (lane & 3) * 8;
        __hip_bfloat16* lz = &zt[buf][0][0] + lane * 8;
        __builtin_amdgcn_global_load_lds((const __attribute__((address_space(1))) unsigned int*)gz,
                                         (__attribute__((address_space(3))) unsigned int*)lz, 16, 0, 0);
        const float* gB = bcb + (r0 + (lane >> 2)) * 32 + (lane & 3) * 4;
        float* lB = &Btl[buf][0][0] + lane * 4;
        __builtin_amdgcn_global_load_lds((const __attribute__((address_space(1))) unsigned int*)gB,
                                         (__attribute__((address_space(3))) unsigned int*)lB, 16, 0, 0);
        const float* gC = bcb + (r0 + (lane >> 2)) * 32 + 16 + (lane & 3) * 4;
        float* lC = &Ctl[buf][0][0] + lane * 4;
        __builtin_amdgcn_global_load_lds((const __attribute__((address_space(1))) unsigned int*)gC,
                                         (__attribute__((address_space(3))) unsigned int*)lC, 16, 0, 0);
      }
    } else {
      if (wv == 0) {
        const __hip_bfloat16* g = u_po + (r0 + (lane >> 2)) * D_INNER + dbase + (lane & 3) * 8;
        __hip_bfloat16* l_ = &dut[buf][0][0] + lane * 8;
        __builtin_amdgcn_global_load_lds((const __attribute__((address_space(1))) unsigned int*)g,
                                         (__attribute__((address_space(3))) unsigned int*)l_, 16, 0, 0);
      } else {
        const float* gB = bcb + (r0 + (lane >> 2)) * 32 + (lane & 3) * 4;
        float* lB = &Btl[buf][0][0] + lane * 4;
        __builtin_amdgcn_global_load_lds((const __attribute__((address_space(1))) unsigned int*)gB,
                                         (__attribute__((address_space(3))) unsigned int*)lB, 16, 0, 0);
      }
    }
  };

  auto sprep = [&](int buf, float dtn) {
    #pragma unroll
    for (int i = 0; i < 2; ++i) {
      int idx = tid + 128 * i;
      int row = idx >> 4, n = idx & 15;
      float dv = __shfl(dtn, row);
      float a  = aexp[n];
      st[buf][row][n] = 1.0f / fmaf(dv * dv, a, 1.0f);
    }
  };

  stage(0, 0);
  float dtn = 0.f;
  if (lane < 16) dtn = dtT[(size_t)h * ROWS + rowbase + lane];
  __syncthreads();
  if (tid < 16) dtt[0][tid] = dtn;
  sprep(0, dtn);
  __syncthreads();

  f32x2 w2[2], ys2[2];
  if constexpr (PHASE == 1) {
    #pragma unroll
    for (int k = 0; k < 2; ++k) { w2[k] = (f32x2){0.f, 0.f}; ys2[k] = (f32x2){0.f, 0.f}; }
  } else {
    #pragma unroll
    for (int k = 0; k < 2; ++k)
      #pragma unroll
      for (int j = 0; j < 2; ++j) {
        size_t i2 = (((size_t)bh * NCH + ch) * 64 + dl) * 16 + (n0 + 2 * k + j);
        float2 s = *(const float2*)&states[i2 * 2];
        w2[k][j] = s.x; ys2[k][j] = s.y;
      }
  }
  int cur = 0;

  for (int t = 0; t < TPC; ++t) {
    if (t + 1 < TPC) {
      stage(t + 1, cur ^ 1);
      if (lane < 16) dtn = dtT[(size_t)h * ROWS + rowbase + (size_t)(t + 1) * T_TILE + lane];
    }
    #pragma unroll 4
    for (int l = 0; l < T_TILE; ++l) {
      float uv  = __bfloat162float(dut[cur][l][dwv]);
      float dtv = dtt[cur][l];
      f32x4 Sv4 = *(const f32x4*)&st [cur][l][n0];
      f32x4 Bv4 = *(const f32x4*)&Btl[cur][l][n0];
      float du = dtv * uv;
      f32x2 S2[2] = { {Sv4[0], Sv4[1]}, {Sv4[2], Sv4[3]} };
      f32x2 B2[2] = { {Bv4[0], Bv4[1]}, {Bv4[2], Bv4[3]} };
      if constexpr (PHASE == 3) {
        f32x4 Cv4 = *(const f32x4*)&Ctl[cur][l][n0];
        f32x2 C2[2] = { {Cv4[0], Cv4[1]}, {Cv4[2], Cv4[3]} };
        f32x2 o2 = {0.f, 0.f};
        #pragma unroll
        for (int k = 0; k < 2; ++k) {
          f32x2 dtA = dtv * A2[k];
          f32x2 tmp = w2[k] - dtA * ys2[k];
          tmp = tmp + du * B2[k];
          w2[k] = S2[k] * tmp;
          ys2[k] = ys2[k] + dtv * w2[k];
          o2 = o2 + ys2[k] * C2[k];
        }
        float o = o2[0] + o2[1];
        float ofin = (ng == 0) ? fmaf(Dh, uv, o) : o;
        opart[l][dwv][ng] = ofin;
      } else {
        #pragma unroll
        for (int k = 0; k < 2; ++k) {
          f32x2 dtA = dtv * A2[k];
          f32x2 tmp = w2[k] - dtA * ys2[k];
          tmp = tmp + du * B2[k];
          w2[k] = S2[k] * tmp;
          ys2[k] = ys2[k] + dtv * w2[k];
        }
      }
    }
    if constexpr (PHASE == 3) {
      #pragma unroll
      for (int i = 0; i < 4; ++i) {
        int l  = (lane >> 4) + 4 * i;
        int dd = wv * 16 + d16;
        f32x4 op = *(const f32x4*)&opart[l][dd][0];
        float zv = __bfloat162float(zt[cur][l][dd]);
        float yv = (op[0] + op[1]) + (op[2] + op[3]);
        u_po[(rowbase + (size_t)t * T_TILE + l) * D_INNER + dbase + dd] =
            __float2bfloat16(yv * siluf(zv));
      }
    }
    __syncthreads();
    if (t + 1 < TPC) {
      if (tid < 16) dtt[cur ^ 1][tid] = dtn;
      sprep(cur ^ 1, dtn);
      __syncthreads();
    }
    cur ^= 1;
  }

  if constexpr (PHASE == 1) {
    #pragma unroll
    for (int k = 0; k < 2; ++k)
      #pragma unroll
      for (int j = 0; j < 2; ++j) {
        size_t i2 = (((size_t)bh * NCH + ch) * 64 + dl) * 16 + (n0 + 2 * k + j);
        *(float2*)&states[i2 * 2] = make_float2(w2[k][j], ys2[k][j]);
      }
  }
}

// ---------------------------------------------------------------- launch
extern "C" void kernel_launch(void* const* d_in, const int* in_sizes, int n_in,
                              void* d_out, int out_size, void* d_ws, size_t ws_size,
                              hipStream_t stream) {
  const float* x     = (const float*)d_in[0];
  const float* n1w   = (const float*)d_in[1];
  const float* wi    = (const float*)d_in[2];
  const float* cw    = (const float*)d_in[3];
  const float* cb    = (const float*)d_in[4];
  const float* A_log = (const float*)d_in[5];
  const float* dtb   = (const float*)d_in[6];
  const float* Dp    = (const float*)d_in[7];
  const float* wo    = (const float*)d_in[8];
  const float* n2w   = (const float*)d_in[9];
  const float* wg    = (const float*)d_in[10];
  const float* wu    = (const float*)d_in[11];
  const float* wd    = (const float*)d_in[12];
  float* out = (float*)d_out;

  char* p = (char*)d_ws;
  auto take = [&](size_t b) { char* q = p; p += (b + 255) & ~(size_t)255; return q; };
  __hip_bfloat16* wbi  = (__hip_bfloat16*)take((size_t)ZX_N * D_MODEL * 2);
  __hip_bfloat16* wbo  = (__hip_bfloat16*)take((size_t)D_MODEL * D_INNER * 2);
  __hip_bfloat16* wgu  = (__hip_bfloat16*)take((size_t)GU_N * D_MODEL * 2);
  __hip_bfloat16* wbd  = (__hip_bfloat16*)take((size_t)D_MODEL * FFN_DIM * 2);
  __hip_bfloat16* h0b  = (__hip_bfloat16*)take((size_t)ROWS * D_MODEL * 2);
  char*           region = take((size_t)84 * 1024 * 1024);
  float*          bcb  = (float*)take((size_t)ROWS * 32 * 4);
  float*          bcraw= (float*)take((size_t)ROWS * 32 * 4);
  float*          dtT  = (float*)take((size_t)ROWS * 32 * 4);
  __hip_bfloat16* po   = (__hip_bfloat16*)take((size_t)ROWS * D_INNER * 2);
  float*          pend = (float*)take((size_t)128 * NCH * 64 * 16 * 2 * 4);
  float*          sini = (float*)take((size_t)128 * NCH * 64 * 16 * 2 * 4);
  float*          Pm   = (float*)take((size_t)128 * NCH * 16 * 4 * 4);
  float*          h0f  = (float*)region;
  __hip_bfloat16* zxb  = (__hip_bfloat16*)region;
  float*          h    = (float*)region;
  __hip_bfloat16* gact = (__hip_bfloat16*)(region + 33554432);

  hipFuncSetAttribute(reinterpret_cast<const void*>(&gemm8<5>),  hipFuncAttributeMaxDynamicSharedMemorySize, 131072);
  hipFuncSetAttribute(reinterpret_cast<const void*>(&gemmT<4>),  hipFuncAttributeMaxDynamicSharedMemorySize, 49152);
  hipFuncSetAttribute(reinterpret_cast<const void*>(&gemm8B<1>), hipFuncAttributeMaxDynamicSharedMemorySize, 131072);

  // all weight conversions in one dispatch
  cvtall_k<<<(Z1 + Z2 + Z3 + Z4 + 255) / 256, 256, 0, stream>>>(wi, wo, wg, wu, wd,
                                                                wbi, wbo, wgu, wbd);

  // mixer
  rmsnorm_k<<<ROWS, 256, 0, stream>>>(x, n1w, h0b, h0f);
  vecproj_k<<<ROWS / 4, 256, 0, stream>>>(h0f, wi, dtb, dtT, bcraw);
  gemm8<5><<<(ROWS / 256) * (ZX_N / 256), 512, 131072, stream>>>(h0b, wbi, zxb,
                                                                 ROWS, ZX_N, D_MODEL);
  duconv_k<<<ROWS * 512 / 256, 256, 0, stream>>>(zxb, cw, cb, po);
  bcdt_k<<<ROWS / 8, 256, 0, stream>>>(bcraw, cw, cb, bcb);
  pk_k<<<BATCH * N_HEADS, 256, 0, stream>>>(dtT, A_log, Pm);
  scan_k<1><<<BATCH * N_HEADS * NCH * 2, 128, 0, stream>>>(zxb, bcb, dtT, A_log, Dp, pend, po);
  prop_k<<<BATCH * N_HEADS * 64 * 16 / 256, 256, 0, stream>>>(Pm, pend, sini);
  scan_k<3><<<BATCH * N_HEADS * NCH * 2, 128, 0, stream>>>(zxb, bcb, dtT, A_log, Dp, sini, po);
  gemm8B<1><<<(ROWS / 256) * (D_MODEL / 128), 512, 131072, stream>>>(po, wbo, h, nullptr, x,
                                                                     ROWS, D_MODEL, D_INNER);
  // FFN
  rmsnorm_k<<<ROWS, 256, 0, stream>>>(h, n2w, h0b, nullptr);
  gemmT<4><<<(ROWS / 256) * (GU_N / 128), 512, 49152, stream>>>(h0b, wgu, gact,
                                                                ROWS, GU_N, D_MODEL);
  gemm8B<1><<<(ROWS / 256) * (D_MODEL / 128), 512, 131072, stream>>>(gact, wbd, out, nullptr, h,
                                                                     ROWS, D_MODEL, FFN_DIM);
}